// Round 7
// baseline (2275.637 us; speedup 1.0000x reference)
//
#include <hip/hip_runtime.h>
#include <math.h>

#define NB 16
#define T  2048
#define D  512
#define BD 64
#define BT (NB*T)  // 32768

// workspace layout (float offsets)
#define OFF_K   0
#define OFF_V   (BT*BD)
#define OFF_Q   (2*BT*BD)
#define OFF_ETA (3*BT*BD)
#define OFF_H   (3*BT*BD + BT)

// gram scratch lives in d_out (64 MB; consumed by ttt before outproj writes):
// per 16-step chunk: KK[256] | KQ[256] | SC[16..pad 256] | KKX[256] | KQX[256]
// KKX/KQX are CROSS-chunk grams vs the NEXT chunk's k/q rows.
#define GSTRIDE 1280
#define NCHUNK  (BT/16)   // 2048

#define RL(x, i) __int_as_float(__builtin_amdgcn_readlane(__float_as_int(x), (i)))

// ---------------- DPP full-wave sum, result broadcast to all lanes ----------
__device__ __forceinline__ float wave_allsum(float x) {
  x += __int_as_float(__builtin_amdgcn_update_dpp(
      0, __float_as_int(x), 0x111, 0xf, 0xf, true));   // row_shr:1
  x += __int_as_float(__builtin_amdgcn_update_dpp(
      0, __float_as_int(x), 0x112, 0xf, 0xf, true));   // row_shr:2
  x += __int_as_float(__builtin_amdgcn_update_dpp(
      0, __float_as_int(x), 0x114, 0xf, 0xf, true));   // row_shr:4
  x += __int_as_float(__builtin_amdgcn_update_dpp(
      0, __float_as_int(x), 0x118, 0xf, 0xf, true));   // row_shr:8
  x += __int_as_float(__builtin_amdgcn_update_dpp(
      0, __float_as_int(x), 0x142, 0xa, 0xf, false));  // row_bcast:15
  x += __int_as_float(__builtin_amdgcn_update_dpp(
      0, __float_as_int(x), 0x143, 0xc, 0xf, false));  // row_bcast:31
  return RL(x, 63);
}

// DS-only barrier (lgkmcnt(0), vmcnt left in flight). Proven r3/r4.
__device__ __forceinline__ void lds_barrier() {
  __builtin_amdgcn_sched_barrier(0);
  __builtin_amdgcn_s_waitcnt(0xC07F);
  __builtin_amdgcn_s_barrier();
  __builtin_amdgcn_sched_barrier(0);
}

// ---------------- projection: K,V,Q = x @ W{k,v,q} + b ----------------
__device__ __forceinline__ void do_proj(const float* __restrict__ W,
                                        const float* __restrict__ bias,
                                        float* __restrict__ Out,
                                        const float* xs, int col, int rg,
                                        size_t row0) {
  float a0 = 0.f, a1 = 0.f, a2 = 0.f, a3 = 0.f;
  for (int d = 0; d < D; d += 4) {
    float w0 = W[(d + 0) * BD + col];
    float w1 = W[(d + 1) * BD + col];
    float w2 = W[(d + 2) * BD + col];
    float w3 = W[(d + 3) * BD + col];
    const float* xb = xs + (rg * 4) * D + d;
    float4 x0 = *(const float4*)(xb);
    float4 x1 = *(const float4*)(xb + D);
    float4 x2 = *(const float4*)(xb + 2 * D);
    float4 x3 = *(const float4*)(xb + 3 * D);
    a0 += x0.x * w0 + x0.y * w1 + x0.z * w2 + x0.w * w3;
    a1 += x1.x * w0 + x1.y * w1 + x1.z * w2 + x1.w * w3;
    a2 += x2.x * w0 + x2.y * w1 + x2.z * w2 + x2.w * w3;
    a3 += x3.x * w0 + x3.y * w1 + x3.z * w2 + x3.w * w3;
  }
  float bb = bias[col];
  Out[(row0 + rg * 4 + 0) * BD + col] = a0 + bb;
  Out[(row0 + rg * 4 + 1) * BD + col] = a1 + bb;
  Out[(row0 + rg * 4 + 2) * BD + col] = a2 + bb;
  Out[(row0 + rg * 4 + 3) * BD + col] = a3 + bb;
}

__global__ __launch_bounds__(256) void proj_kernel(
    const float* __restrict__ x,
    const float* __restrict__ Wk, const float* __restrict__ bk,
    const float* __restrict__ Wv, const float* __restrict__ bv,
    const float* __restrict__ Wq, const float* __restrict__ bq,
    float* __restrict__ Kout, float* __restrict__ Vout,
    float* __restrict__ Qout) {
  __shared__ __align__(16) float xs[16 * D];  // 32 KB
  const int tid = threadIdx.x;
  const size_t row0 = (size_t)blockIdx.x * 16;
  const float4* xg = (const float4*)(x + row0 * D);
  float4* xs4 = (float4*)xs;
#pragma unroll
  for (int i = 0; i < 8; i++) xs4[i * 256 + tid] = xg[i * 256 + tid];
  __syncthreads();
  const int col = tid & 63;
  const int rg = tid >> 6;
  do_proj(Wk, bk, Kout, xs, col, rg, row0);
  do_proj(Wv, bv, Vout, xs, col, rg, row0);
  do_proj(Wq, bq, Qout, xs, col, rg, row0);
}

// ---------------- eta = sigmoid(x . lr_w + lr_b) ----------------
__global__ __launch_bounds__(256) void eta_kernel(const float* __restrict__ x,
                                                  const float* __restrict__ lr_w,
                                                  const float* __restrict__ lr_b,
                                                  float* __restrict__ eta) {
  const int tid = threadIdx.x;
  const int lane = tid & 63;
  const int wv = tid >> 6;
  const size_t r = (size_t)blockIdx.x * 4 + wv;
  const float* xr = x + r * D + lane * 8;
  float4 a = *(const float4*)xr;
  float4 b = *(const float4*)(xr + 4);
  const float* lw = lr_w + lane * 8;
  float4 la = *(const float4*)lw;
  float4 lb = *(const float4*)(lw + 4);
  float p = a.x * la.x + a.y * la.y + a.z * la.z + a.w * la.w +
            b.x * lb.x + b.y * lb.y + b.z * lb.z + b.w * lb.w;
#pragma unroll
  for (int m = 32; m > 0; m >>= 1) p += __shfl_xor(p, m, 64);
  if (lane == 0) eta[r] = 1.0f / (1.0f + expf(-(p + lr_b[0])));
}

// ---------------- gram kernel: per 16-step chunk, precompute -------------
//   KK[i][t]=k_i.k_t  KQ[i][t]=k_i.q_t  SC[t]=sum g*(k+b-v)
//   KKX[i][t]=k_i.k'_t  KQX[i][t]=k_i.q'_t   (primes = NEXT chunk's rows)
__global__ __launch_bounds__(256) void gram_kernel(
    const float* __restrict__ K, const float* __restrict__ V,
    const float* __restrict__ Q, const float* __restrict__ ln_g,
    const float* __restrict__ ln_b, float* __restrict__ G) {
  __shared__ __align__(16) float sK[16][64], sQ[16][64], sV[16][64];
  __shared__ __align__(16) float sK2[16][64], sQ2[16][64];
  __shared__ float sg[64], sb[64];
  const int tid = threadIdx.x;
  const size_t row0 = (size_t)blockIdx.x * 16;
  const bool last = (blockIdx.x % 128) == 127;
  const size_t row0n = last ? row0 : row0 + 16;  // clamp: values unused at last
  ((float4*)sK)[tid]  = ((const float4*)(K + row0 * BD))[tid];
  ((float4*)sQ)[tid]  = ((const float4*)(Q + row0 * BD))[tid];
  ((float4*)sV)[tid]  = ((const float4*)(V + row0 * BD))[tid];
  ((float4*)sK2)[tid] = ((const float4*)(K + row0n * BD))[tid];
  ((float4*)sQ2)[tid] = ((const float4*)(Q + row0n * BD))[tid];
  if (tid < 64) { sg[tid] = ln_g[tid]; sb[tid] = ln_b[tid]; }
  __syncthreads();
  const int i = tid >> 4, t = tid & 15;
  float kk = 0.f, kq = 0.f, kkx = 0.f, kqx = 0.f;
#pragma unroll
  for (int d = 0; d < 64; d += 4) {
    float4 a4 = *(const float4*)&sK[i][d];
    float4 b4 = *(const float4*)&sK[t][d];
    float4 c4 = *(const float4*)&sQ[t][d];
    float4 d4 = *(const float4*)&sK2[t][d];
    float4 e4 = *(const float4*)&sQ2[t][d];
    kk  += a4.x * b4.x + a4.y * b4.y + a4.z * b4.z + a4.w * b4.w;
    kq  += a4.x * c4.x + a4.y * c4.y + a4.z * c4.z + a4.w * c4.w;
    kkx += a4.x * d4.x + a4.y * d4.y + a4.z * d4.z + a4.w * d4.w;
    kqx += a4.x * e4.x + a4.y * e4.y + a4.z * e4.z + a4.w * e4.w;
  }
  size_t gb = (size_t)blockIdx.x * GSTRIDE;
  G[gb + i * 16 + t] = kk;
  G[gb + 256 + i * 16 + t] = kq;
  G[gb + 768 + i * 16 + t] = kkx;
  G[gb + 1024 + i * 16 + t] = kqx;
  if (tid < 16) {
    float sc = 0.f;
    for (int d = 0; d < 64; d++)
      sc += sg[d] * (sK[tid][d] + sb[d] - sV[tid][d]);
    G[gb + 512 + tid] = sc;
  }
}

// ---------------- sequential TTT scan: role-split waves -------------------
// Round 11. r4/r6 counters pinned the model: wall = per-wave instr stream
// x 2cy / busy(0.68-0.79). So: shrink the stream of the wave carrying the
// serial chain. 5 waves/chain: waves 0-3 = HELPERS (16-col W slices), wave 4
// = COMPUTE (serial chain only). Phase A runs ONE CHUNK AHEAD vs W_start(n-1);
// compute applies cross-chunk corrections via KKX gram.
//   compute/step: c0 + 5 allsums + scalar chain + u-gather(16 cross + <t
//                 within, readlane) + coef ds_write.   (~120 instr)
//   helpers/chunk (batched): W-update(coefs n-1), phase A(n+1) with ds_add
//                 accumulation into fin (no combine phase), flush(n-1) with
//                 owner-cut p-gather, coop staging, fin zeroing. (~92/step)
// ONE barrier per chunk. Buffer slot audit (all cross-wave deps cross >=1
// barrier; same-chunk slots distinct):
//   rows[4]: stage(n+2)@n | c0 reads n | W-upd reads n-1 | phaseA reads n+1
//   fU[3]: add(n+1)@n | compute reads n | zero(n+2)@n
//   fP[4]: add(n+1)@n | flush(n-1) reads n-1 | zero(n+2)@n
//   cfl[3]: compute writes n | helpers read n-1 (W-upd/flush-cur) and n-2
//           (flush-cross)
__global__ __launch_bounds__(320, 1)
void ttt_seq_kernel(
    const float* __restrict__ Kin, const float* __restrict__ Vin,
    const float* __restrict__ Qin, const float* __restrict__ eta_in,
    const float* __restrict__ W0, const float* __restrict__ ln_g,
    const float* __restrict__ ln_b, float* __restrict__ Hout,
    const float* __restrict__ gram) {
  __shared__ __align__(16) float rK[4][16][64];   // 16 KB
  __shared__ __align__(16) float rQ[4][16][64];   // 16 KB
  __shared__ __align__(16) float rV[4][16][64];   // 16 KB
  __shared__ __align__(16) float fU[3][16][64];   // 12 KB
  __shared__ __align__(16) float fP[4][16][64];   // 16 KB
  __shared__ __align__(16) float cfl[3][16][64];  // 12 KB  => 88 KB total
  const int tid = threadIdx.x;
  const int lane = tid & 63;
  const int wid = __builtin_amdgcn_readfirstlane(tid) >> 6;  // 0..4
  const bool isHelper = wid < 4;
  const int h = wid;  // helper id / W col-slice [16h,16h+16)
  const int b = blockIdx.x;

  const float g = ln_g[lane];
  const float bet = ln_b[lane];
  const float a = g * g;

  const size_t base = (size_t)b * T * BD;
  const size_t ebase = (size_t)b * T;
  const size_t gbase = (size_t)b * 128 * GSTRIDE;

  float w[16];        // helpers only
  float A2 = 0.f;     // compute only
  if (isHelper) {
    const float4* w04 = (const float4*)(W0 + (size_t)lane * BD + h * 16);
#pragma unroll
    for (int i = 0; i < 4; i++) {
      float4 t4 = w04[i];
      w[4 * i] = t4.x; w[4 * i + 1] = t4.y; w[4 * i + 2] = t4.z; w[4 * i + 3] = t4.w;
    }
    // prologue: stage rows(0),(1); zero fU[0],fU[1], fP[0],fP[1]
    ((float4*)rK[0])[tid] = ((const float4*)(Kin + base))[tid];
    ((float4*)rQ[0])[tid] = ((const float4*)(Qin + base))[tid];
    ((float4*)rV[0])[tid] = ((const float4*)(Vin + base))[tid];
    ((float4*)rK[1])[tid] = ((const float4*)(Kin + base + 1024))[tid];
    ((float4*)rQ[1])[tid] = ((const float4*)(Qin + base + 1024))[tid];
    ((float4*)rV[1])[tid] = ((const float4*)(Vin + base + 1024))[tid];
    float4 z4 = make_float4(0.f, 0.f, 0.f, 0.f);
    ((float4*)fU[0])[tid] = z4; ((float4*)fU[1])[tid] = z4;
    ((float4*)fP[0])[tid] = z4; ((float4*)fP[1])[tid] = z4;
  } else {
    A2 = wave_allsum(a);
  }
  lds_barrier();
  if (isHelper) {
    // phase A(0) vs W0 -> fU[0], fP[0]
#pragma unroll
    for (int r = 0; r < 16; r++) {
      const float4* kp = (const float4*)&rK[0][r][h * 16];
      const float4* qp = (const float4*)&rQ[0][r][h * 16];
      float4 k0 = kp[0], k1 = kp[1], k2 = kp[2], k3 = kp[3];
      float4 q0 = qp[0], q1 = qp[1], q2 = qp[2], q3 = qp[3];
      float u0s = k0.x*w[0]+k0.y*w[1]+k0.z*w[2]+k0.w*w[3];
      float u1s = k1.x*w[4]+k1.y*w[5]+k1.z*w[6]+k1.w*w[7];
      float u2s = k2.x*w[8]+k2.y*w[9]+k2.z*w[10]+k2.w*w[11];
      float u3s = k3.x*w[12]+k3.y*w[13]+k3.z*w[14]+k3.w*w[15];
      float p0s = q0.x*w[0]+q0.y*w[1]+q0.z*w[2]+q0.w*w[3];
      float p1s = q1.x*w[4]+q1.y*w[5]+q1.z*w[6]+q1.w*w[7];
      float p2s = q2.x*w[8]+q2.y*w[9]+q2.z*w[10]+q2.w*w[11];
      float p3s = q3.x*w[12]+q3.y*w[13]+q3.z*w[14]+q3.w*w[15];
      atomicAdd(&fU[0][r][lane], (u0s + u1s) + (u2s + u3s));
      atomicAdd(&fP[0][r][lane], (p0s + p1s) + (p2s + p3s));
    }
  }
  lds_barrier();

  // compute-wave persistent state
  float coefs_prev[16], coefs_cur[16];
#pragma unroll
  for (int i = 0; i < 16; i++) coefs_prev[i] = 0.f;

  for (int n = 0; n < 128; n++) {
    const int rs = n & 3, rs1 = (n + 1) & 3, rs2 = (n + 2) & 3, rsm = (n - 1) & 3;
    const int fu = n % 3, fu1 = (n + 1) % 3, fu2 = (n + 2) % 3;
    const int fp1 = (n + 1) & 3, fpm = (n - 1) & 3, fp2 = (n + 2) & 3;

    if (isHelper) {
      // staging loads rows(n+2) (overruns past K/Q/V regions stay in d_ws)
      float4 sk_ = ((const float4*)(Kin + base + (size_t)(n + 2) * 1024))[tid];
      float4 sq_ = ((const float4*)(Qin + base + (size_t)(n + 2) * 1024))[tid];
      float4 sv_ = ((const float4*)(Vin + base + (size_t)(n + 2) * 1024))[tid];

      // coefs generations from LDS
      float cfH[16], cfHp[16];
      if (n >= 1) {
        const int s1 = (n - 1) % 3;
#pragma unroll
        for (int i = 0; i < 16; i++) cfH[i] = cfl[s1][i][lane];
      } else {
#pragma unroll
        for (int i = 0; i < 16; i++) cfH[i] = 0.f;
      }
      if (n >= 2) {
        const int s2 = (n - 2) % 3;
#pragma unroll
        for (int i = 0; i < 16; i++) cfHp[i] = cfl[s2][i][lane];
      } else {
#pragma unroll
        for (int i = 0; i < 16; i++) cfHp[i] = 0.f;
      }

      // ---- flush(n-1): owner-cut p-gather + output LN ----
      if (n >= 1) {
        const size_t gbm  = gbase + (size_t)(n - 1) * GSTRIDE;
        const size_t gbm2 = gbase + (size_t)(n >= 2 ? n - 2 : 0) * GSTRIDE;
        float KQc[4], KQXc[4];
#pragma unroll
        for (int j = 0; j < 4; j++) {
          KQc[j]  = gram[gbm  + 256  + (size_t)lane * 16 + 4 * j + h];
          KQXc[j] = gram[gbm2 + 1024 + (size_t)lane * 16 + 4 * j + h];
        }
#pragma unroll
        for (int j = 0; j < 4; j++) {
          const int s = 4 * j + h;
          float u2 = fP[fpm][4 * j + h][lane];
#pragma unroll
          for (int i = 0; i < 16; i++) u2 += cfHp[i] * RL(KQXc[j], i);
#pragma unroll
          for (int i = 0; i < 16; i++) {
            float term = cfH[i] * RL(KQc[j], i);
            u2 += (i <= s) ? term : 0.f;
          }
          float Su2  = wave_allsum(u2);
          float Suu2 = wave_allsum(u2 * u2);
          float mu2 = Su2 * (1.0f / 64);
          float rstd2 = rsqrtf(Suu2 * (1.0f / 64) - mu2 * mu2 + 1e-6f);
          float qv = rQ[rsm][s][lane];
          Hout[base + (size_t)((n - 1) * 16 + s) * BD + lane] =
              qv + (u2 - mu2) * rstd2 * g + bet;
        }
        // ---- W-update with coefs(n-1) (rows n-1) -> W_start(n) ----
#pragma unroll
        for (int i = 0; i < 16; i++) {
          const float4* kp = (const float4*)&rK[rsm][i][h * 16];
          float4 k0 = kp[0], k1 = kp[1], k2 = kp[2], k3 = kp[3];
          float cf = cfH[i];
          w[0]  += cf * k0.x; w[1]  += cf * k0.y; w[2]  += cf * k0.z; w[3]  += cf * k0.w;
          w[4]  += cf * k1.x; w[5]  += cf * k1.y; w[6]  += cf * k1.z; w[7]  += cf * k1.w;
          w[8]  += cf * k2.x; w[9]  += cf * k2.y; w[10] += cf * k2.z; w[11] += cf * k2.w;
          w[12] += cf * k3.x; w[13] += cf * k3.y; w[14] += cf * k3.z; w[15] += cf * k3.w;
        }
      }

      // ---- phase A(n+1) vs W_start(n) -> ds_add into fU[fu1], fP[fp1] ----
      if (n < 127) {
#pragma unroll
        for (int r = 0; r < 16; r++) {
          const float4* kp = (const float4*)&rK[rs1][r][h * 16];
          const float4* qp = (const float4*)&rQ[rs1][r][h * 16];
          float4 k0 = kp[0], k1 = kp[1], k2 = kp[2], k3 = kp[3];
          float4 q0 = qp[0], q1 = qp[1], q2 = qp[2], q3 = qp[3];
          float u0s = k0.x*w[0]+k0.y*w[1]+k0.z*w[2]+k0.w*w[3];
          float u1s = k1.x*w[4]+k1.y*w[5]+k1.z*w[6]+k1.w*w[7];
          float u2s = k2.x*w[8]+k2.y*w[9]+k2.z*w[10]+k2.w*w[11];
          float u3s = k3.x*w[12]+k3.y*w[13]+k3.z*w[14]+k3.w*w[15];
          float p0s = q0.x*w[0]+q0.y*w[1]+q0.z*w[2]+q0.w*w[3];
          float p1s = q1.x*w[4]+q1.y*w[5]+q1.z*w[6]+q1.w*w[7];
          float p2s = q2.x*w[8]+q2.y*w[9]+q2.z*w[10]+q2.w*w[11];
          float p3s = q3.x*w[12]+q3.y*w[13]+q3.z*w[14]+q3.w*w[15];
          atomicAdd(&fU[fu1][r][lane], (u0s + u1s) + (u2s + u3s));
          atomicAdd(&fP[fp1][r][lane], (p0s + p1s) + (p2s + p3s));
        }
      }

      // zero fin slots for chunk n+2's adds
      float4 z4 = make_float4(0.f, 0.f, 0.f, 0.f);
      ((float4*)fU[fu2])[tid] = z4;
      ((float4*)fP[fp2])[tid] = z4;
      // staging writes rows(n+2) (compiler inserts vmcnt before these)
      ((float4*)rK[rs2])[tid] = sk_;
      ((float4*)rQ[rs2])[tid] = sq_;
      ((float4*)rV[rs2])[tid] = sv_;
    } else {
      // ================= COMPUTE wave: 16 serial steps =================
      const size_t gb  = gbase + (size_t)n * GSTRIDE;
      const size_t gbp = gbase + (size_t)(n >= 1 ? n - 1 : 0) * GSTRIDE;
      float KKr[16];  // row t used for within-gather at step t (t>=1)
#pragma unroll
      for (int t = 1; t < 16; t++) KKr[t] = gram[gb + t * 16 + lane];
      float KKXc[16];
#pragma unroll
      for (int t = 0; t < 16; t++)
        KKXc[t] = gram[gbp + 768 + (size_t)lane * 16 + t];
      float SCv = gram[gb + 512 + lane];
      float ecv = eta_in[ebase + n * 16 + (lane & 15)];

      float u0p[16];
#pragma unroll
      for (int t = 0; t < 16; t++) u0p[t] = fU[fu][t][lane];

#pragma unroll
      for (int t = 0; t < 16; t++) {
        float kc = rK[rs][t][lane];
        float vc = rV[rs][t][lane];
        float c0 = g * (kc + bet - vc);
        float u = u0p[t];
#pragma unroll
        for (int i = 0; i < 16; i++) u += coefs_prev[i] * RL(KKXc[t], i);
#pragma unroll
        for (int i = 0; i < t; i++) u += coefs_cur[i] * RL(KKr[t], i);

        float Su   = wave_allsum(u);
        float Suu  = wave_allsum(u * u);
        float Sau  = wave_allsum(a * u);
        float Sauu = wave_allsum(a * u * u);
        float Scu  = wave_allsum(c0 * u);
        float Sc   = RL(SCv, t);
        float ecur = RL(ecv, t);

        float mu = Su * (1.0f / 64);
        float var = Suu * (1.0f / 64) - mu * mu;
        float rstd = rsqrtf(var + 1e-6f);
        float xh = (u - mu) * rstd;
        float Axh   = rstd * (Sau - mu * A2);
        float Scxh  = rstd * (Scu - mu * Sc);
        float Saxh2 = rstd * rstd * (Sauu - 2.0f * mu * Sau + mu * mu * A2);
        float s1 = (2.0f / 64) * (Sc + Axh);
        float s2 = (2.0f / 64) * (Scxh + Saxh2);
        float dxh = (2.0f / 64) * (c0 + a * xh);
        float dldu = rstd * (dxh - s1 * (1.0f / 64) - xh * (s2 * (1.0f / 64)));
        float coef = -ecur * dldu;
        coefs_cur[t] = coef;
        cfl[n % 3][t][lane] = coef;
      }
#pragma unroll
      for (int i = 0; i < 16; i++) coefs_prev[i] = coefs_cur[i];
    }
    lds_barrier();
  }

  // epilogue: flush(127) on helpers (coefs(127) in cfl[127%3], coefs(126) in
  // cfl[126%3]; fP/rQ slot 127&3=3 untouched by staging(128/129)->slots 0/1)
  if (isHelper) {
    float cfH[16], cfHp[16];
#pragma unroll
    for (int i = 0; i < 16; i++) { cfH[i] = cfl[127 % 3][i][lane]; cfHp[i] = cfl[126 % 3][i][lane]; }
    const size_t gbm  = gbase + (size_t)127 * GSTRIDE;
    const size_t gbm2 = gbase + (size_t)126 * GSTRIDE;
    float KQc[4], KQXc[4];
#pragma unroll
    for (int j = 0; j < 4; j++) {
      KQc[j]  = gram[gbm  + 256  + (size_t)lane * 16 + 4 * j + h];
      KQXc[j] = gram[gbm2 + 1024 + (size_t)lane * 16 + 4 * j + h];
    }
#pragma unroll
    for (int j = 0; j < 4; j++) {
      const int s = 4 * j + h;
      float u2 = fP[127 & 3][s][lane];
#pragma unroll
      for (int i = 0; i < 16; i++) u2 += cfHp[i] * RL(KQXc[j], i);
#pragma unroll
      for (int i = 0; i < 16; i++) {
        float term = cfH[i] * RL(KQc[j], i);
        u2 += (i <= s) ? term : 0.f;
      }
      float Su2  = wave_allsum(u2);
      float Suu2 = wave_allsum(u2 * u2);
      float mu2 = Su2 * (1.0f / 64);
      float rstd2 = rsqrtf(Suu2 * (1.0f / 64) - mu2 * mu2 + 1e-6f);
      float qv = rQ[127 & 3][s][lane];
      Hout[base + (size_t)(127 * 16 + s) * BD + lane] =
          qv + (u2 - mu2) * rstd2 * g + bet;
    }
  }
}

// ---------------- out projection: z = H @ Wo + bo ----------------
__global__ __launch_bounds__(256) void outproj_kernel(
    const float* __restrict__ H, const float* __restrict__ Wo,
    const float* __restrict__ bo, float* __restrict__ out) {
  __shared__ __align__(16) float ht[16 * BD];  // 4 KB
  const int tid = threadIdx.x;
  const size_t row0 = (size_t)blockIdx.x * 16;
  ((float4*)ht)[tid] = ((const float4*)(H + row0 * BD))[tid];
  __syncthreads();
  float acc0[16], acc1[16];
#pragma unroll
  for (int r = 0; r < 16; r++) { acc0[r] = 0.f; acc1[r] = 0.f; }
  for (int kk = 0; kk < BD; kk++) {
    float w0 = Wo[kk * D + tid];
    float w1 = Wo[kk * D + tid + 256];
#pragma unroll
    for (int r = 0; r < 16; r++) {
      float hv = ht[r * BD + kk];
      acc0[r] += hv * w0;
      acc1[r] += hv * w1;
    }
  }
  float b0 = bo[tid], b1 = bo[tid + 256];
#pragma unroll
  for (int r = 0; r < 16; r++) {
    out[(row0 + r) * D + tid] = acc0[r] + b0;
    out[(row0 + r) * D + tid + 256] = acc1[r] + b1;
  }
}

extern "C" void kernel_launch(void* const* d_in, const int* in_sizes, int n_in,
                              void* d_out, int out_size, void* d_ws,
                              size_t ws_size, hipStream_t stream) {
  (void)in_sizes; (void)n_in; (void)out_size; (void)ws_size;
  const float* x    = (const float*)d_in[0];
  const float* Wk   = (const float*)d_in[1];
  const float* bk   = (const float*)d_in[2];
  const float* Wv   = (const float*)d_in[3];
  const float* bv   = (const float*)d_in[4];
  const float* Wq   = (const float*)d_in[5];
  const float* bq   = (const float*)d_in[6];
  const float* Wo   = (const float*)d_in[7];
  const float* bo   = (const float*)d_in[8];
  const float* ln_g = (const float*)d_in[9];
  const float* ln_b = (const float*)d_in[10];
  const float* lr_w = (const float*)d_in[11];
  const float* lr_b = (const float*)d_in[12];
  const float* W0   = (const float*)d_in[13];

  float* ws  = (float*)d_ws;
  float* Kb  = ws + OFF_K;
  float* Vb  = ws + OFF_V;
  float* Qb  = ws + OFF_Q;
  float* ETA = ws + OFF_ETA;
  float* Hb  = ws + OFF_H;
  float* out = (float*)d_out;
  float* GRAM = out;  // scratch inside d_out; consumed before outproj writes

  proj_kernel<<<BT / 16, 256, 0, stream>>>(x, Wk, bk, Wv, bv, Wq, bq, Kb, Vb, Qb);
  eta_kernel<<<BT / 4, 256, 0, stream>>>(x, lr_w, lr_b, ETA);
  gram_kernel<<<NCHUNK, 256, 0, stream>>>(Kb, Vb, Qb, ln_g, ln_b, GRAM);
  ttt_seq_kernel<<<NB, 320, 0, stream>>>(Kb, Vb, Qb, ETA, W0, ln_g, ln_b, Hb, GRAM);
  outproj_kernel<<<BT / 16, 256, 0, stream>>>(Hb, Wo, bo, out);
}

// Round 8
// 1621.189 us; speedup vs baseline: 1.4037x; 1.4037x over previous
//
#include <hip/hip_runtime.h>
#include <math.h>

#define NB 16
#define T  2048
#define D  512
#define BD 64
#define BT (NB*T)  // 32768

// workspace layout (float offsets)
#define OFF_K   0
#define OFF_V   (BT*BD)
#define OFF_Q   (2*BT*BD)
#define OFF_ETA (3*BT*BD)
#define OFF_H   (3*BT*BD + BT)
// total floats = 4*BT*BD + BT = 8,421,376  (~33.7 MB)

// gram scratch lives in d_out (64 MB; overwritten later by outproj):
// per 16-step chunk: KK[16*16] | KQ[16*16] | SC[16] | pad -> 544 floats
#define GSTRIDE 544
#define NCHUNK  (BT/16)   // 2048

#define RL(x, i) __int_as_float(__builtin_amdgcn_readlane(__float_as_int(x), (i)))

// ---------------- DPP full-wave sum, result broadcast to all lanes ----------
__device__ __forceinline__ float wave_allsum(float x) {
  x += __int_as_float(__builtin_amdgcn_update_dpp(
      0, __float_as_int(x), 0x111, 0xf, 0xf, true));   // row_shr:1
  x += __int_as_float(__builtin_amdgcn_update_dpp(
      0, __float_as_int(x), 0x112, 0xf, 0xf, true));   // row_shr:2
  x += __int_as_float(__builtin_amdgcn_update_dpp(
      0, __float_as_int(x), 0x114, 0xf, 0xf, true));   // row_shr:4
  x += __int_as_float(__builtin_amdgcn_update_dpp(
      0, __float_as_int(x), 0x118, 0xf, 0xf, true));   // row_shr:8
  x += __int_as_float(__builtin_amdgcn_update_dpp(
      0, __float_as_int(x), 0x142, 0xa, 0xf, false));  // row_bcast:15 -> rows 1,3
  x += __int_as_float(__builtin_amdgcn_update_dpp(
      0, __float_as_int(x), 0x143, 0xc, 0xf, false));  // row_bcast:31 -> rows 2,3
  return RL(x, 63);
}

// DS-only barrier: waits lgkmcnt(0) (all loop lgkm ops are DS), leaves vmcnt
// in flight. Proven r3/r4.
__device__ __forceinline__ void lds_barrier() {
  __builtin_amdgcn_sched_barrier(0);
  __builtin_amdgcn_s_waitcnt(0xC07F);  // vmcnt=63 (no wait), expcnt=7, lgkmcnt=0
  __builtin_amdgcn_s_barrier();
  __builtin_amdgcn_sched_barrier(0);
}

// ---------------- fused projection: K,V,Q = x @ W{k,v,q} + b ----------------
// Round 12: the old per-projection do_proj re-read the staged x-tile from LDS
// 3x (24KB/thread -> ~12.6 GB LDS traffic ~ 180us at the 69TB/s LDS ceiling).
// ONE d-loop computing all three projections shares the x reads (3x less LDS
// traffic); accumulation order per projection is bit-identical to before.
__global__ __launch_bounds__(256) void proj_kernel(
    const float* __restrict__ x,
    const float* __restrict__ Wk, const float* __restrict__ bk,
    const float* __restrict__ Wv, const float* __restrict__ bv,
    const float* __restrict__ Wq, const float* __restrict__ bq,
    float* __restrict__ Kout, float* __restrict__ Vout,
    float* __restrict__ Qout) {
  __shared__ __align__(16) float xs[16 * D];  // 32 KB
  const int tid = threadIdx.x;
  const size_t row0 = (size_t)blockIdx.x * 16;
  const float4* xg = (const float4*)(x + row0 * D);
  float4* xs4 = (float4*)xs;
#pragma unroll
  for (int i = 0; i < 8; i++) xs4[i * 256 + tid] = xg[i * 256 + tid];
  __syncthreads();
  const int col = tid & 63;
  const int rg = tid >> 6;  // 4 row-groups of 4 rows

  float ak0 = 0.f, ak1 = 0.f, ak2 = 0.f, ak3 = 0.f;
  float av0 = 0.f, av1 = 0.f, av2 = 0.f, av3 = 0.f;
  float aq0 = 0.f, aq1 = 0.f, aq2 = 0.f, aq3 = 0.f;
  for (int d = 0; d < D; d += 4) {
    float wk0 = Wk[(d + 0) * BD + col];
    float wk1 = Wk[(d + 1) * BD + col];
    float wk2 = Wk[(d + 2) * BD + col];
    float wk3 = Wk[(d + 3) * BD + col];
    float wv0 = Wv[(d + 0) * BD + col];
    float wv1 = Wv[(d + 1) * BD + col];
    float wv2 = Wv[(d + 2) * BD + col];
    float wv3 = Wv[(d + 3) * BD + col];
    float wq0 = Wq[(d + 0) * BD + col];
    float wq1 = Wq[(d + 1) * BD + col];
    float wq2 = Wq[(d + 2) * BD + col];
    float wq3 = Wq[(d + 3) * BD + col];
    const float* xb = xs + (rg * 4) * D + d;
    float4 x0 = *(const float4*)(xb);
    float4 x1 = *(const float4*)(xb + D);
    float4 x2 = *(const float4*)(xb + 2 * D);
    float4 x3 = *(const float4*)(xb + 3 * D);
    ak0 += x0.x * wk0 + x0.y * wk1 + x0.z * wk2 + x0.w * wk3;
    ak1 += x1.x * wk0 + x1.y * wk1 + x1.z * wk2 + x1.w * wk3;
    ak2 += x2.x * wk0 + x2.y * wk1 + x2.z * wk2 + x2.w * wk3;
    ak3 += x3.x * wk0 + x3.y * wk1 + x3.z * wk2 + x3.w * wk3;
    av0 += x0.x * wv0 + x0.y * wv1 + x0.z * wv2 + x0.w * wv3;
    av1 += x1.x * wv0 + x1.y * wv1 + x1.z * wv2 + x1.w * wv3;
    av2 += x2.x * wv0 + x2.y * wv1 + x2.z * wv2 + x2.w * wv3;
    av3 += x3.x * wv0 + x3.y * wv1 + x3.z * wv2 + x3.w * wv3;
    aq0 += x0.x * wq0 + x0.y * wq1 + x0.z * wq2 + x0.w * wq3;
    aq1 += x1.x * wq0 + x1.y * wq1 + x1.z * wq2 + x1.w * wq3;
    aq2 += x2.x * wq0 + x2.y * wq1 + x2.z * wq2 + x2.w * wq3;
    aq3 += x3.x * wq0 + x3.y * wq1 + x3.z * wq2 + x3.w * wq3;
  }
  float bbk = bk[col], bbv = bv[col], bbq = bq[col];
  const size_t r0 = row0 + rg * 4;
  Kout[(r0 + 0) * BD + col] = ak0 + bbk;
  Kout[(r0 + 1) * BD + col] = ak1 + bbk;
  Kout[(r0 + 2) * BD + col] = ak2 + bbk;
  Kout[(r0 + 3) * BD + col] = ak3 + bbk;
  Vout[(r0 + 0) * BD + col] = av0 + bbv;
  Vout[(r0 + 1) * BD + col] = av1 + bbv;
  Vout[(r0 + 2) * BD + col] = av2 + bbv;
  Vout[(r0 + 3) * BD + col] = av3 + bbv;
  Qout[(r0 + 0) * BD + col] = aq0 + bbq;
  Qout[(r0 + 1) * BD + col] = aq1 + bbq;
  Qout[(r0 + 2) * BD + col] = aq2 + bbq;
  Qout[(r0 + 3) * BD + col] = aq3 + bbq;
}

// ---------------- eta = sigmoid(x . lr_w + lr_b) ----------------
__global__ __launch_bounds__(256) void eta_kernel(const float* __restrict__ x,
                                                  const float* __restrict__ lr_w,
                                                  const float* __restrict__ lr_b,
                                                  float* __restrict__ eta) {
  const int tid = threadIdx.x;
  const int lane = tid & 63;
  const int wv = tid >> 6;
  const size_t r = (size_t)blockIdx.x * 4 + wv;  // one wave per row
  const float* xr = x + r * D + lane * 8;
  float4 a = *(const float4*)xr;
  float4 b = *(const float4*)(xr + 4);
  const float* lw = lr_w + lane * 8;
  float4 la = *(const float4*)lw;
  float4 lb = *(const float4*)(lw + 4);
  float p = a.x * la.x + a.y * la.y + a.z * la.z + a.w * la.w +
            b.x * lb.x + b.y * lb.y + b.z * lb.z + b.w * lb.w;
#pragma unroll
  for (int m = 32; m > 0; m >>= 1) p += __shfl_xor(p, m, 64);
  if (lane == 0) eta[r] = 1.0f / (1.0f + expf(-(p + lr_b[0])));
}

// ---------------- gram kernel: per 16-step chunk, precompute -------------
//   KK[i][t] = k_i . k_t ; KQ[i][t] = k_i . q_t ; SC[t] = sum g*(k+b-v)
__global__ __launch_bounds__(256) void gram_kernel(
    const float* __restrict__ K, const float* __restrict__ V,
    const float* __restrict__ Q, const float* __restrict__ ln_g,
    const float* __restrict__ ln_b, float* __restrict__ G) {
  __shared__ __align__(16) float sK[16][64], sQ[16][64], sV[16][64];
  __shared__ float sg[64], sb[64];
  const int tid = threadIdx.x;
  const size_t row0 = (size_t)blockIdx.x * 16;
  ((float4*)sK)[tid] = ((const float4*)(K + row0 * BD))[tid];
  ((float4*)sQ)[tid] = ((const float4*)(Q + row0 * BD))[tid];
  ((float4*)sV)[tid] = ((const float4*)(V + row0 * BD))[tid];
  if (tid < 64) { sg[tid] = ln_g[tid]; sb[tid] = ln_b[tid]; }
  __syncthreads();
  const int i = tid >> 4, t = tid & 15;
  float kk = 0.f, kq = 0.f;
#pragma unroll
  for (int d = 0; d < 64; d += 4) {
    float4 a4 = *(const float4*)&sK[i][d];
    float4 b4 = *(const float4*)&sK[t][d];
    float4 c4 = *(const float4*)&sQ[t][d];
    kk += a4.x * b4.x + a4.y * b4.y + a4.z * b4.z + a4.w * b4.w;
    kq += a4.x * c4.x + a4.y * c4.y + a4.z * c4.z + a4.w * c4.w;
  }
  size_t gb = (size_t)blockIdx.x * GSTRIDE;
  G[gb + i * 16 + t] = kk;
  G[gb + 256 + i * 16 + t] = kq;
  if (tid < 16) {
    float sc = 0.f;
    for (int d = 0; d < 64; d++)
      sc += sg[d] * (sK[tid][d] + sb[d] - sV[tid][d]);
    G[gb + 512 + tid] = sc;
  }
}

// ---------------- sequential TTT scan: chunked delta-rule, 4 waves --------
// Round 12: REVERT to the r4 structure (proven 1096us; r5/r6/r7 structural
// variants all regressed -- lockstep siblings, barrier-coupled chains, and
// role-split all lost more to sync/gather than they saved). Only delta vs r4:
// the per-step p-scatter (avg ~17 instr/step) is replaced by 4 owner-running
// scalars pcorr[fi] (<=4 RL+FMA/step, most compile-time elided) -- each wave
// accumulates corrections only for the 4 steps it owns; added to the base at
// flush. u-scatter, allsums, W-update, staging identical to r4.
__global__ __launch_bounds__(256, 1)
void ttt_seq_kernel(
    const float* __restrict__ Kin, const float* __restrict__ Vin,
    const float* __restrict__ Qin, const float* __restrict__ eta_in,
    const float* __restrict__ W0, const float* __restrict__ ln_g,
    const float* __restrict__ ln_b, float* __restrict__ Hout,
    const float* __restrict__ gram) {
  __shared__ __align__(16) float2 part2[16][4][64];  // 32 KB partials
  __shared__ __align__(16) float kls[16][64];        // 4 KB k rows
  __shared__ __align__(16) float qls[16][64];        // 4 KB q rows
  const int tid = threadIdx.x;
  const int lane = tid & 63;
  const int wvu = __builtin_amdgcn_readfirstlane(tid) >> 6;
  const int b = blockIdx.x;

  // W slice: w[4i+j] = W0[lane*BD + 16*wvu + 4i+j]
  float w[16];
  {
    const float4* w04 = (const float4*)(W0 + (size_t)lane * BD + wvu * 16);
#pragma unroll
    for (int i = 0; i < 4; i++) {
      float4 t4 = w04[i];
      w[4 * i] = t4.x; w[4 * i + 1] = t4.y; w[4 * i + 2] = t4.z; w[4 * i + 3] = t4.w;
    }
  }
  const float g = ln_g[lane];
  const float bet = ln_b[lane];
  const float a = g * g;
  const float A2 = wave_allsum(a);

  size_t base = (size_t)b * T * BD;   // advances BD per step
  size_t ebase = (size_t)b * T;

  // per-lane rows of the current chunk (reloaded in-place for chunk+1 during
  // phase B, period-16 ring -> zero extra registers)
  float krow[16], qrow[16], vrow[16];
#pragma unroll
  for (int r = 0; r < 16; r++) {
    krow[r] = Kin[base + r * BD + lane];
    qrow[r] = Qin[base + r * BD + lane];
    vrow[r] = Vin[base + r * BD + lane];
  }
  float ev  = eta_in[ebase + lane];
  float evn = eta_in[ebase + 64 + lane];

  float u2sv[4], qsv[4];  // deferred phase-2 state (4 owned steps per wave)

  for (int c64 = 0; c64 < 32; c64++) {
    size_t eoff = (size_t)(c64 + 2) * 64;
    if (eoff >= T) eoff = 0;
    float ev2 = eta_in[ebase + eoff + lane];

    for (int cc = 0; cc < 4; cc++) {
      // ---- gram loads for this chunk (consumed in phase B; phase A covers) --
      const size_t gb = (size_t)(b * 128 + c64 * 4 + cc) * GSTRIDE;
      float KKr[15], KQr[16];
#pragma unroll
      for (int t = 0; t < 15; t++) KKr[t] = gram[gb + t * 16 + lane];
#pragma unroll
      for (int t = 0; t < 16; t++) KQr[t] = gram[gb + 256 + t * 16 + lane];
      float SCv = gram[gb + 512 + lane];

      // ---- phase A: stage rows to LDS (all waves write identical values:
      // benign; each wave's own in-order DS writes make its reads correct) --
#pragma unroll
      for (int r = 0; r < 16; r++) {
        kls[r][lane] = krow[r];
        qls[r][lane] = qrow[r];
      }
      // 3-deep uniform-read pipeline (broadcast ds_read_b128, conflict-free)
      float4 kuf[3][4], quf[3][4];
#pragma unroll
      for (int r = 0; r < 3; r++) {
        const float4* kp = (const float4*)&kls[r][wvu * 16];
        const float4* qp = (const float4*)&qls[r][wvu * 16];
#pragma unroll
        for (int i = 0; i < 4; i++) { kuf[r][i] = kp[i]; quf[r][i] = qp[i]; }
      }
      float u0[16], p0[16];
#pragma unroll
      for (int r = 0; r < 16; r++) {
        const int bf = r % 3;
        float uu0 = 0.f, uu1 = 0.f, uu2 = 0.f, uu3 = 0.f;
        float pp0 = 0.f, pp1 = 0.f, pp2 = 0.f, pp3 = 0.f;
#pragma unroll
        for (int i = 0; i < 4; i++) {
          uu0 += kuf[bf][i].x * w[4 * i + 0];
          uu1 += kuf[bf][i].y * w[4 * i + 1];
          uu2 += kuf[bf][i].z * w[4 * i + 2];
          uu3 += kuf[bf][i].w * w[4 * i + 3];
          pp0 += quf[bf][i].x * w[4 * i + 0];
          pp1 += quf[bf][i].y * w[4 * i + 1];
          pp2 += quf[bf][i].z * w[4 * i + 2];
          pp3 += quf[bf][i].w * w[4 * i + 3];
        }
        part2[r][wvu][lane] = make_float2((uu0 + uu1) + (uu2 + uu3),
                                          (pp0 + pp1) + (pp2 + pp3));
        if (r < 13) {
          const float4* kp = (const float4*)&kls[r + 3][wvu * 16];
          const float4* qp = (const float4*)&qls[r + 3][wvu * 16];
#pragma unroll
          for (int i = 0; i < 4; i++) { kuf[bf][i] = kp[i]; quf[bf][i] = qp[i]; }
        }
      }

      lds_barrier();  // partials visible

      // combine partials -> full u, p
#pragma unroll
      for (int r = 0; r < 16; r++) {
        float2 pA = part2[r][0][lane];
        float2 pB = part2[r][1][lane];
        float2 pC = part2[r][2][lane];
        float2 pD = part2[r][3][lane];
        u0[r] = (pA.x + pB.x) + (pC.x + pD.x);
        p0[r] = (pA.y + pB.y) + (pC.y + pD.y);
      }

      float pcorr[4];
#pragma unroll
      for (int fi = 0; fi < 4; fi++) pcorr[fi] = 0.f;

      // ---- phase B: 16 serial steps, no barriers ----
#pragma unroll
      for (int t = 0; t < 16; t++) {
        float u = u0[t];
        float kcur = krow[t], vcur = vrow[t], qcur = qrow[t];
        float ecur = RL(ev, cc * 16 + t);
        float c0 = g * (kcur + bet - vcur);

        float Su   = wave_allsum(u);
        float Suu  = wave_allsum(u * u);
        float Sau  = wave_allsum(a * u);
        float Sauu = wave_allsum(a * u * u);
        float Scu  = wave_allsum(c0 * u);
        float Sc   = RL(SCv, t);

        float mu = Su * (1.0f / 64);
        float var = Suu * (1.0f / 64) - mu * mu;
        float rstd = rsqrtf(var + 1e-6f);
        float xh = (u - mu) * rstd;
        float Axh   = rstd * (Sau - mu * A2);
        float Scxh  = rstd * (Scu - mu * Sc);
        float Saxh2 = rstd * rstd * (Sauu - 2.0f * mu * Sau + mu * mu * A2);
        float s1 = (2.0f / 64) * (Sc + Axh);
        float s2 = (2.0f / 64) * (Scxh + Saxh2);
        float dxh = (2.0f / 64) * (c0 + a * xh);
        float dldu = rstd * (dxh - s1 * (1.0f / 64) - xh * (s2 * (1.0f / 64)));
        float coef = -ecur * dldu;

        // critical correction first: u for step t+1
        if (t < 15)
          u0[t + 1] += coef * RL(KKr[t], t + 1);
        // remaining u-scatter (off critical path; fills stall slots)
#pragma unroll
        for (int s = t + 2; s < 16; s++)
          u0[s] += coef * RL(KKr[t], s);

        // owner-running p-corrections: wave's 4 owned steps town=4*fi+wvu.
        // Condition t <= town: compile-time true when t <= 4*fi, compile-time
        // false when t > 4*fi+3; runtime-uniform otherwise.
#pragma unroll
        for (int fi = 0; fi < 4; fi++) {
          if (t <= 4 * fi + 3) {           // compile-time prune
            const int town = 4 * fi + wvu; // uniform
            float term = coef * RL(KQr[t], town);
            if (t <= town) pcorr[fi] += term;
          }
        }

        // W-slice update via uniform LDS read of row t (off critical path;
        // next use of w is next chunk's phase A)
        {
          const float4* kp = (const float4*)&kls[t][wvu * 16];
#pragma unroll
          for (int i = 0; i < 4; i++) {
            float4 k4 = kp[i];
            w[4 * i + 0] += coef * k4.x;
            w[4 * i + 1] += coef * k4.y;
            w[4 * i + 2] += coef * k4.z;
            w[4 * i + 3] += coef * k4.w;
          }
        }

        if ((t & 3) == wvu) { u2sv[t >> 2] = p0[t]; qsv[t >> 2] = qcur; }

        // reload row t for the NEXT chunk (per-lane; 16 steps of cover)
        krow[t] = Kin[base + 16 * BD + lane];
        qrow[t] = Qin[base + 16 * BD + lane];
        vrow[t] = Vin[base + 16 * BD + lane];
        base += BD;
      }

      // ---- deferred phase-2 flush: each wave finalizes its 4 owned steps --
#pragma unroll
      for (int fi = 0; fi < 4; fi++) {
        float u2 = u2sv[fi] + pcorr[fi];
        float Su2  = wave_allsum(u2);
        float Suu2 = wave_allsum(u2 * u2);
        float mu2 = Su2 * (1.0f / 64);
        float rstd2 = rsqrtf(Suu2 * (1.0f / 64) - mu2 * mu2 + 1e-6f);
        int tt = 4 * fi + wvu;
        Hout[base - (size_t)(16 - tt) * BD + lane] =
            qsv[fi] + (u2 - mu2) * rstd2 * g + bet;
      }

      // protect kls/qls/part2 (single-buffered) against next chunk's writes
      lds_barrier();
    }
    ev = evn; evn = ev2;
  }
}

// ---------------- out projection: z = H @ Wo + bo ----------------
__global__ __launch_bounds__(256) void outproj_kernel(
    const float* __restrict__ H, const float* __restrict__ Wo,
    const float* __restrict__ bo, float* __restrict__ out) {
  __shared__ __align__(16) float ht[16 * BD];  // 4 KB
  const int tid = threadIdx.x;
  const size_t row0 = (size_t)blockIdx.x * 16;
  ((float4*)ht)[tid] = ((const float4*)(H + row0 * BD))[tid];
  __syncthreads();
  float acc0[16], acc1[16];
#pragma unroll
  for (int r = 0; r < 16; r++) { acc0[r] = 0.f; acc1[r] = 0.f; }
  for (int kk = 0; kk < BD; kk++) {
    float w0 = Wo[kk * D + tid];
    float w1 = Wo[kk * D + tid + 256];
#pragma unroll
    for (int r = 0; r < 16; r++) {
      float hv = ht[r * BD + kk];
      acc0[r] += hv * w0;
      acc1[r] += hv * w1;
    }
  }
  float b0 = bo[tid], b1 = bo[tid + 256];
#pragma unroll
  for (int r = 0; r < 16; r++) {
    out[(row0 + r) * D + tid] = acc0[r] + b0;
    out[(row0 + r) * D + tid + 256] = acc1[r] + b1;
  }
}

extern "C" void kernel_launch(void* const* d_in, const int* in_sizes, int n_in,
                              void* d_out, int out_size, void* d_ws,
                              size_t ws_size, hipStream_t stream) {
  (void)in_sizes; (void)n_in; (void)out_size; (void)ws_size;
  const float* x    = (const float*)d_in[0];
  const float* Wk   = (const float*)d_in[1];
  const float* bk   = (const float*)d_in[2];
  const float* Wv   = (const float*)d_in[3];
  const float* bv   = (const float*)d_in[4];
  const float* Wq   = (const float*)d_in[5];
  const float* bq   = (const float*)d_in[6];
  const float* Wo   = (const float*)d_in[7];
  const float* bo   = (const float*)d_in[8];
  const float* ln_g = (const float*)d_in[9];
  const float* ln_b = (const float*)d_in[10];
  const float* lr_w = (const float*)d_in[11];
  const float* lr_b = (const float*)d_in[12];
  const float* W0   = (const float*)d_in[13];

  float* ws  = (float*)d_ws;
  float* Kb  = ws + OFF_K;
  float* Vb  = ws + OFF_V;
  float* Qb  = ws + OFF_Q;
  float* ETA = ws + OFF_ETA;
  float* Hb  = ws + OFF_H;
  float* out = (float*)d_out;
  float* GRAM = out;  // scratch inside d_out; overwritten later by outproj

  proj_kernel<<<BT / 16, 256, 0, stream>>>(x, Wk, bk, Wv, bv, Wq, bq, Kb, Vb, Qb);
  eta_kernel<<<BT / 4, 256, 0, stream>>>(x, lr_w, lr_b, ETA);
  gram_kernel<<<NCHUNK, 256, 0, stream>>>(Kb, Vb, Qb, ln_g, ln_b, GRAM);
  ttt_seq_kernel<<<NB, 256, 0, stream>>>(Kb, Vb, Qb, ETA, W0, ln_g, ln_b, Hb, GRAM);
  outproj_kernel<<<BT / 16, 256, 0, stream>>>(Hb, Wo, bo, out);
}

// Round 9
// 1402.515 us; speedup vs baseline: 1.6225x; 1.1559x over previous
//
#include <hip/hip_runtime.h>
#include <math.h>

#define NB 16
#define T  2048
#define D  512
#define BD 64
#define BT (NB*T)  // 32768

// workspace layout (float offsets)
#define OFF_K   0
#define OFF_V   (BT*BD)
#define OFF_Q   (2*BT*BD)
#define OFF_ETA (3*BT*BD)
#define OFF_H   (3*BT*BD + BT)
// total floats = 4*BT*BD + BT = 8,421,376  (~33.7 MB)

// gram scratch lives in d_out (64 MB; overwritten later by outproj):
// per 16-step chunk: KK[16*16] | KQ[16*16] | SC[16] | pad -> 544 floats
#define GSTRIDE 544
#define NCHUNK  (BT/16)   // 2048

#define RL(x, i) __int_as_float(__builtin_amdgcn_readlane(__float_as_int(x), (i)))

// ---------------- DPP full-wave sum, result broadcast to all lanes ----------
__device__ __forceinline__ float wave_allsum(float x) {
  x += __int_as_float(__builtin_amdgcn_update_dpp(
      0, __float_as_int(x), 0x111, 0xf, 0xf, true));   // row_shr:1
  x += __int_as_float(__builtin_amdgcn_update_dpp(
      0, __float_as_int(x), 0x112, 0xf, 0xf, true));   // row_shr:2
  x += __int_as_float(__builtin_amdgcn_update_dpp(
      0, __float_as_int(x), 0x114, 0xf, 0xf, true));   // row_shr:4
  x += __int_as_float(__builtin_amdgcn_update_dpp(
      0, __float_as_int(x), 0x118, 0xf, 0xf, true));   // row_shr:8
  x += __int_as_float(__builtin_amdgcn_update_dpp(
      0, __float_as_int(x), 0x142, 0xa, 0xf, false));  // row_bcast:15 -> rows 1,3
  x += __int_as_float(__builtin_amdgcn_update_dpp(
      0, __float_as_int(x), 0x143, 0xc, 0xf, false));  // row_bcast:31 -> rows 2,3
  return RL(x, 63);
}

// DS-only barrier: waits lgkmcnt(0) (all loop lgkm ops are DS), leaves vmcnt
// in flight. Proven r3/r4.
__device__ __forceinline__ void lds_barrier() {
  __builtin_amdgcn_sched_barrier(0);
  __builtin_amdgcn_s_waitcnt(0xC07F);  // vmcnt=63 (no wait), expcnt=7, lgkmcnt=0
  __builtin_amdgcn_s_barrier();
  __builtin_amdgcn_sched_barrier(0);
}

// -------- fused projection + eta + gram (5 dispatches -> 3) ---------------
// Round 13: r8 showed the ~330us non-ttt bucket is insensitive to proj-only
// optimization -- it is spread across 4 extra dispatches + their kernel
// times. This block IS one 16-row gram chunk and already holds x in LDS and
// K/V/Q in registers, so eta (reads xs, not HBM: -64MB) and gram (bit-exact
// copy of the standalone kernel's summation on an LDS copy of K/Q/V) fold in
// for free. K/V/Q projection accumulation order identical to r8/r4 lineage.
__global__ __launch_bounds__(256) void proj_kernel(
    const float* __restrict__ x,
    const float* __restrict__ Wk, const float* __restrict__ bk,
    const float* __restrict__ Wv, const float* __restrict__ bv,
    const float* __restrict__ Wq, const float* __restrict__ bq,
    const float* __restrict__ lr_w, const float* __restrict__ lr_b,
    const float* __restrict__ ln_g, const float* __restrict__ ln_b,
    float* __restrict__ Kout, float* __restrict__ Vout,
    float* __restrict__ Qout, float* __restrict__ eta,
    float* __restrict__ G) {
  __shared__ __align__(16) float xs[16 * D];               // 32 KB
  __shared__ __align__(16) float sK[16][64], sQ[16][64], sV[16][64];  // 12 KB
  __shared__ float sg[64], sb[64];
  const int tid = threadIdx.x;
  const size_t row0 = (size_t)blockIdx.x * 16;
  const float4* xg = (const float4*)(x + row0 * D);
  float4* xs4 = (float4*)xs;
#pragma unroll
  for (int i = 0; i < 8; i++) xs4[i * 256 + tid] = xg[i * 256 + tid];
  if (tid < 64) { sg[tid] = ln_g[tid]; sb[tid] = ln_b[tid]; }
  __syncthreads();
  const int col = tid & 63;
  const int rg = tid >> 6;  // 4 row-groups of 4 rows
  const int lane = tid & 63;

  float ak0 = 0.f, ak1 = 0.f, ak2 = 0.f, ak3 = 0.f;
  float av0 = 0.f, av1 = 0.f, av2 = 0.f, av3 = 0.f;
  float aq0 = 0.f, aq1 = 0.f, aq2 = 0.f, aq3 = 0.f;
  for (int d = 0; d < D; d += 4) {
    float wk0 = Wk[(d + 0) * BD + col];
    float wk1 = Wk[(d + 1) * BD + col];
    float wk2 = Wk[(d + 2) * BD + col];
    float wk3 = Wk[(d + 3) * BD + col];
    float wv0 = Wv[(d + 0) * BD + col];
    float wv1 = Wv[(d + 1) * BD + col];
    float wv2 = Wv[(d + 2) * BD + col];
    float wv3 = Wv[(d + 3) * BD + col];
    float wq0 = Wq[(d + 0) * BD + col];
    float wq1 = Wq[(d + 1) * BD + col];
    float wq2 = Wq[(d + 2) * BD + col];
    float wq3 = Wq[(d + 3) * BD + col];
    const float* xb = xs + (rg * 4) * D + d;
    float4 x0 = *(const float4*)(xb);
    float4 x1 = *(const float4*)(xb + D);
    float4 x2 = *(const float4*)(xb + 2 * D);
    float4 x3 = *(const float4*)(xb + 3 * D);
    ak0 += x0.x * wk0 + x0.y * wk1 + x0.z * wk2 + x0.w * wk3;
    ak1 += x1.x * wk0 + x1.y * wk1 + x1.z * wk2 + x1.w * wk3;
    ak2 += x2.x * wk0 + x2.y * wk1 + x2.z * wk2 + x2.w * wk3;
    ak3 += x3.x * wk0 + x3.y * wk1 + x3.z * wk2 + x3.w * wk3;
    av0 += x0.x * wv0 + x0.y * wv1 + x0.z * wv2 + x0.w * wv3;
    av1 += x1.x * wv0 + x1.y * wv1 + x1.z * wv2 + x1.w * wv3;
    av2 += x2.x * wv0 + x2.y * wv1 + x2.z * wv2 + x2.w * wv3;
    av3 += x3.x * wv0 + x3.y * wv1 + x3.z * wv2 + x3.w * wv3;
    aq0 += x0.x * wq0 + x0.y * wq1 + x0.z * wq2 + x0.w * wq3;
    aq1 += x1.x * wq0 + x1.y * wq1 + x1.z * wq2 + x1.w * wq3;
    aq2 += x2.x * wq0 + x2.y * wq1 + x2.z * wq2 + x2.w * wq3;
    aq3 += x3.x * wq0 + x3.y * wq1 + x3.z * wq2 + x3.w * wq3;
  }
  float bbk = bk[col], bbv = bv[col], bbq = bq[col];
  const size_t r0 = row0 + rg * 4;
  float k0v = ak0 + bbk, k1v = ak1 + bbk, k2v = ak2 + bbk, k3v = ak3 + bbk;
  float v0v = av0 + bbv, v1v = av1 + bbv, v2v = av2 + bbv, v3v = av3 + bbv;
  float q0v = aq0 + bbq, q1v = aq1 + bbq, q2v = aq2 + bbq, q3v = aq3 + bbq;
  Kout[(r0 + 0) * BD + col] = k0v;
  Kout[(r0 + 1) * BD + col] = k1v;
  Kout[(r0 + 2) * BD + col] = k2v;
  Kout[(r0 + 3) * BD + col] = k3v;
  Vout[(r0 + 0) * BD + col] = v0v;
  Vout[(r0 + 1) * BD + col] = v1v;
  Vout[(r0 + 2) * BD + col] = v2v;
  Vout[(r0 + 3) * BD + col] = v3v;
  Qout[(r0 + 0) * BD + col] = q0v;
  Qout[(r0 + 1) * BD + col] = q1v;
  Qout[(r0 + 2) * BD + col] = q2v;
  Qout[(r0 + 3) * BD + col] = q3v;
  // stage K/V/Q tile to LDS for the gram phase
  const int lr = rg * 4;
  sK[lr + 0][col] = k0v; sK[lr + 1][col] = k1v;
  sK[lr + 2][col] = k2v; sK[lr + 3][col] = k3v;
  sV[lr + 0][col] = v0v; sV[lr + 1][col] = v1v;
  sV[lr + 2][col] = v2v; sV[lr + 3][col] = v3v;
  sQ[lr + 0][col] = q0v; sQ[lr + 1][col] = q1v;
  sQ[lr + 2][col] = q2v; sQ[lr + 3][col] = q3v;

  // ---- eta for this wave's 4 rows (identical math to old eta_kernel,
  // x values from the staged LDS copy) ----
  {
    const float* lw = lr_w + lane * 8;
    float4 la = *(const float4*)lw;
    float4 lb = *(const float4*)(lw + 4);
    float lrb0 = lr_b[0];
#pragma unroll
    for (int j = 0; j < 4; j++) {
      const float* xr = xs + (size_t)(rg * 4 + j) * D + lane * 8;
      float4 a = *(const float4*)xr;
      float4 b2 = *(const float4*)(xr + 4);
      float p = a.x * la.x + a.y * la.y + a.z * la.z + a.w * la.w +
                b2.x * lb.x + b2.y * lb.y + b2.z * lb.z + b2.w * lb.w;
#pragma unroll
      for (int m = 32; m > 0; m >>= 1) p += __shfl_xor(p, m, 64);
      if (lane == 0) eta[row0 + rg * 4 + j] = 1.0f / (1.0f + expf(-(p + lrb0)));
    }
  }
  __syncthreads();

  // ---- gram phase: bit-identical to the old standalone gram_kernel ----
  const int gi = tid >> 4, gt = tid & 15;
  float kk = 0.f, kq = 0.f;
#pragma unroll
  for (int d = 0; d < 64; d += 4) {
    float4 a4 = *(const float4*)&sK[gi][d];
    float4 b4 = *(const float4*)&sK[gt][d];
    float4 c4 = *(const float4*)&sQ[gt][d];
    kk += a4.x * b4.x + a4.y * b4.y + a4.z * b4.z + a4.w * b4.w;
    kq += a4.x * c4.x + a4.y * c4.y + a4.z * c4.z + a4.w * c4.w;
  }
  size_t gb = (size_t)blockIdx.x * GSTRIDE;
  G[gb + gi * 16 + gt] = kk;
  G[gb + 256 + gi * 16 + gt] = kq;
  if (tid < 16) {
    float sc = 0.f;
    for (int d = 0; d < 64; d++)
      sc += sg[d] * (sK[tid][d] + sb[d] - sV[tid][d]);
    G[gb + 512 + tid] = sc;
  }
}

// ---------------- sequential TTT scan: chunked delta-rule, 4 waves --------
// Round 13: EXACT restore of the r4 structure (proven 1096us; r5-r8 variants
// all regressed). Do not touch phase B.
__global__ __launch_bounds__(256, 1)
void ttt_seq_kernel(
    const float* __restrict__ Kin, const float* __restrict__ Vin,
    const float* __restrict__ Qin, const float* __restrict__ eta_in,
    const float* __restrict__ W0, const float* __restrict__ ln_g,
    const float* __restrict__ ln_b, float* __restrict__ Hout,
    const float* __restrict__ gram) {
  __shared__ __align__(16) float2 part2[16][4][64];  // 32 KB partials
  __shared__ __align__(16) float kls[16][64];        // 4 KB k rows
  __shared__ __align__(16) float qls[16][64];        // 4 KB q rows
  const int tid = threadIdx.x;
  const int lane = tid & 63;
  const int wvu = __builtin_amdgcn_readfirstlane(tid) >> 6;
  const int b = blockIdx.x;

  // W slice: w[4i+j] = W0[lane*BD + 16*wvu + 4i+j]
  float w[16];
  {
    const float4* w04 = (const float4*)(W0 + (size_t)lane * BD + wvu * 16);
#pragma unroll
    for (int i = 0; i < 4; i++) {
      float4 t4 = w04[i];
      w[4 * i] = t4.x; w[4 * i + 1] = t4.y; w[4 * i + 2] = t4.z; w[4 * i + 3] = t4.w;
    }
  }
  const float g = ln_g[lane];
  const float bet = ln_b[lane];
  const float a = g * g;
  const float A2 = wave_allsum(a);

  size_t base = (size_t)b * T * BD;   // advances BD per step
  size_t ebase = (size_t)b * T;

  // per-lane rows of the current chunk (reloaded in-place for chunk+1 during
  // phase B, period-16 ring -> zero extra registers)
  float krow[16], qrow[16], vrow[16];
#pragma unroll
  for (int r = 0; r < 16; r++) {
    krow[r] = Kin[base + r * BD + lane];
    qrow[r] = Qin[base + r * BD + lane];
    vrow[r] = Vin[base + r * BD + lane];
  }
  float ev  = eta_in[ebase + lane];
  float evn = eta_in[ebase + 64 + lane];

  float u2sv[4], qsv[4];  // deferred phase-2 state (4 owned steps per wave)

  for (int c64 = 0; c64 < 32; c64++) {
    size_t eoff = (size_t)(c64 + 2) * 64;
    if (eoff >= T) eoff = 0;
    float ev2 = eta_in[ebase + eoff + lane];

    for (int cc = 0; cc < 4; cc++) {
      // ---- gram loads for this chunk (consumed in phase B; phase A covers) --
      const size_t gb = (size_t)(b * 128 + c64 * 4 + cc) * GSTRIDE;
      float KKr[15], KQr[16];
#pragma unroll
      for (int t = 0; t < 15; t++) KKr[t] = gram[gb + t * 16 + lane];
#pragma unroll
      for (int t = 0; t < 16; t++) KQr[t] = gram[gb + 256 + t * 16 + lane];
      float SCv = gram[gb + 512 + lane];

      // ---- phase A: stage rows to LDS (all waves write identical values:
      // benign; each wave's own in-order DS writes make its reads correct) --
#pragma unroll
      for (int r = 0; r < 16; r++) {
        kls[r][lane] = krow[r];
        qls[r][lane] = qrow[r];
      }
      // 3-deep uniform-read pipeline (broadcast ds_read_b128, conflict-free)
      float4 kuf[3][4], quf[3][4];
#pragma unroll
      for (int r = 0; r < 3; r++) {
        const float4* kp = (const float4*)&kls[r][wvu * 16];
        const float4* qp = (const float4*)&qls[r][wvu * 16];
#pragma unroll
        for (int i = 0; i < 4; i++) { kuf[r][i] = kp[i]; quf[r][i] = qp[i]; }
      }
      float u0[16], p0[16];
#pragma unroll
      for (int r = 0; r < 16; r++) {
        const int bf = r % 3;
        float uu0 = 0.f, uu1 = 0.f, uu2 = 0.f, uu3 = 0.f;
        float pp0 = 0.f, pp1 = 0.f, pp2 = 0.f, pp3 = 0.f;
#pragma unroll
        for (int i = 0; i < 4; i++) {
          uu0 += kuf[bf][i].x * w[4 * i + 0];
          uu1 += kuf[bf][i].y * w[4 * i + 1];
          uu2 += kuf[bf][i].z * w[4 * i + 2];
          uu3 += kuf[bf][i].w * w[4 * i + 3];
          pp0 += quf[bf][i].x * w[4 * i + 0];
          pp1 += quf[bf][i].y * w[4 * i + 1];
          pp2 += quf[bf][i].z * w[4 * i + 2];
          pp3 += quf[bf][i].w * w[4 * i + 3];
        }
        part2[r][wvu][lane] = make_float2((uu0 + uu1) + (uu2 + uu3),
                                          (pp0 + pp1) + (pp2 + pp3));
        if (r < 13) {
          const float4* kp = (const float4*)&kls[r + 3][wvu * 16];
          const float4* qp = (const float4*)&qls[r + 3][wvu * 16];
#pragma unroll
          for (int i = 0; i < 4; i++) { kuf[bf][i] = kp[i]; quf[bf][i] = qp[i]; }
        }
      }

      lds_barrier();  // partials visible

      // combine partials -> full u, p
#pragma unroll
      for (int r = 0; r < 16; r++) {
        float2 pA = part2[r][0][lane];
        float2 pB = part2[r][1][lane];
        float2 pC = part2[r][2][lane];
        float2 pD = part2[r][3][lane];
        u0[r] = (pA.x + pB.x) + (pC.x + pD.x);
        p0[r] = (pA.y + pB.y) + (pC.y + pD.y);
      }

      // ---- phase B: 16 serial steps, no barriers ----
#pragma unroll
      for (int t = 0; t < 16; t++) {
        float u = u0[t];
        float kcur = krow[t], vcur = vrow[t], qcur = qrow[t];
        float ecur = RL(ev, cc * 16 + t);
        float c0 = g * (kcur + bet - vcur);

        float Su   = wave_allsum(u);
        float Suu  = wave_allsum(u * u);
        float Sau  = wave_allsum(a * u);
        float Sauu = wave_allsum(a * u * u);
        float Scu  = wave_allsum(c0 * u);
        float Sc   = RL(SCv, t);

        float mu = Su * (1.0f / 64);
        float var = Suu * (1.0f / 64) - mu * mu;
        float rstd = rsqrtf(var + 1e-6f);
        float xh = (u - mu) * rstd;
        float Axh   = rstd * (Sau - mu * A2);
        float Scxh  = rstd * (Scu - mu * Sc);
        float Saxh2 = rstd * rstd * (Sauu - 2.0f * mu * Sau + mu * mu * A2);
        float s1 = (2.0f / 64) * (Sc + Axh);
        float s2 = (2.0f / 64) * (Scxh + Saxh2);
        float dxh = (2.0f / 64) * (c0 + a * xh);
        float dldu = rstd * (dxh - s1 * (1.0f / 64) - xh * (s2 * (1.0f / 64)));
        float coef = -ecur * dldu;

        // critical correction first: u for step t+1
        if (t < 15)
          u0[t + 1] += coef * RL(KKr[t], t + 1);
        // lazy corrections (off critical path)
#pragma unroll
        for (int s = t + 2; s < 16; s++)
          u0[s] += coef * RL(KKr[t], s);
#pragma unroll
        for (int s = t; s < 16; s++)
          p0[s] += coef * RL(KQr[t], s);

        // W-slice update via uniform LDS read of row t (off critical path;
        // next use of w is next chunk's phase A)
        {
          const float4* kp = (const float4*)&kls[t][wvu * 16];
#pragma unroll
          for (int i = 0; i < 4; i++) {
            float4 k4 = kp[i];
            w[4 * i + 0] += coef * k4.x;
            w[4 * i + 1] += coef * k4.y;
            w[4 * i + 2] += coef * k4.z;
            w[4 * i + 3] += coef * k4.w;
          }
        }

        if ((t & 3) == wvu) { u2sv[t >> 2] = p0[t]; qsv[t >> 2] = qcur; }

        // reload row t for the NEXT chunk (per-lane; 16 steps of cover)
        krow[t] = Kin[base + 16 * BD + lane];
        qrow[t] = Qin[base + 16 * BD + lane];
        vrow[t] = Vin[base + 16 * BD + lane];
        base += BD;
      }

      // ---- deferred phase-2 flush: each wave finalizes its 4 owned steps --
#pragma unroll
      for (int fi = 0; fi < 4; fi++) {
        float u2 = u2sv[fi];
        float Su2  = wave_allsum(u2);
        float Suu2 = wave_allsum(u2 * u2);
        float mu2 = Su2 * (1.0f / 64);
        float rstd2 = rsqrtf(Suu2 * (1.0f / 64) - mu2 * mu2 + 1e-6f);
        int tt = 4 * fi + wvu;
        Hout[base - (size_t)(16 - tt) * BD + lane] =
            qsv[fi] + (u2 - mu2) * rstd2 * g + bet;
      }

      // protect kls/qls/part2 (single-buffered) against next chunk's writes
      lds_barrier();
    }
    ev = evn; evn = ev2;
  }
}

// ---------------- out projection: z = H @ Wo + bo ----------------
// Round 13: ht reads vectorized (ds_read_b128; 4x fewer LDS instructions,
// same broadcast pattern, accumulation order preserved via sequential adds).
__global__ __launch_bounds__(256) void outproj_kernel(
    const float* __restrict__ H, const float* __restrict__ Wo,
    const float* __restrict__ bo, float* __restrict__ out) {
  __shared__ __align__(16) float ht[16 * BD];  // 4 KB
  const int tid = threadIdx.x;
  const size_t row0 = (size_t)blockIdx.x * 16;
  ((float4*)ht)[tid] = ((const float4*)(H + row0 * BD))[tid];
  __syncthreads();
  float acc0[16], acc1[16];
#pragma unroll
  for (int r = 0; r < 16; r++) { acc0[r] = 0.f; acc1[r] = 0.f; }
  for (int kk4 = 0; kk4 < 16; kk4++) {
    float w00 = Wo[(4 * kk4 + 0) * D + tid];
    float w01 = Wo[(4 * kk4 + 1) * D + tid];
    float w02 = Wo[(4 * kk4 + 2) * D + tid];
    float w03 = Wo[(4 * kk4 + 3) * D + tid];
    float w10 = Wo[(4 * kk4 + 0) * D + tid + 256];
    float w11 = Wo[(4 * kk4 + 1) * D + tid + 256];
    float w12 = Wo[(4 * kk4 + 2) * D + tid + 256];
    float w13 = Wo[(4 * kk4 + 3) * D + tid + 256];
#pragma unroll
    for (int r = 0; r < 16; r++) {
      float4 hv = *(const float4*)&ht[r * BD + 4 * kk4];
      acc0[r] += hv.x * w00;
      acc0[r] += hv.y * w01;
      acc0[r] += hv.z * w02;
      acc0[r] += hv.w * w03;
      acc1[r] += hv.x * w10;
      acc1[r] += hv.y * w11;
      acc1[r] += hv.z * w12;
      acc1[r] += hv.w * w13;
    }
  }
  float b0 = bo[tid], b1 = bo[tid + 256];
#pragma unroll
  for (int r = 0; r < 16; r++) {
    out[(row0 + r) * D + tid] = acc0[r] + b0;
    out[(row0 + r) * D + tid + 256] = acc1[r] + b1;
  }
}

extern "C" void kernel_launch(void* const* d_in, const int* in_sizes, int n_in,
                              void* d_out, int out_size, void* d_ws,
                              size_t ws_size, hipStream_t stream) {
  (void)in_sizes; (void)n_in; (void)out_size; (void)ws_size;
  const float* x    = (const float*)d_in[0];
  const float* Wk   = (const float*)d_in[1];
  const float* bk   = (const float*)d_in[2];
  const float* Wv   = (const float*)d_in[3];
  const float* bv   = (const float*)d_in[4];
  const float* Wq   = (const float*)d_in[5];
  const float* bq   = (const float*)d_in[6];
  const float* Wo   = (const float*)d_in[7];
  const float* bo   = (const float*)d_in[8];
  const float* ln_g = (const float*)d_in[9];
  const float* ln_b = (const float*)d_in[10];
  const float* lr_w = (const float*)d_in[11];
  const float* lr_b = (const float*)d_in[12];
  const float* W0   = (const float*)d_in[13];

  float* ws  = (float*)d_ws;
  float* Kb  = ws + OFF_K;
  float* Vb  = ws + OFF_V;
  float* Qb  = ws + OFF_Q;
  float* ETA = ws + OFF_ETA;
  float* Hb  = ws + OFF_H;
  float* out = (float*)d_out;
  float* GRAM = out;  // scratch inside d_out; overwritten later by outproj

  proj_kernel<<<NCHUNK, 256, 0, stream>>>(x, Wk, bk, Wv, bv, Wq, bq,
                                          lr_w, lr_b, ln_g, ln_b,
                                          Kb, Vb, Qb, ETA, GRAM);
  ttt_seq_kernel<<<NB, 256, 0, stream>>>(Kb, Vb, Qb, ETA, W0, ln_g, ln_b, Hb, GRAM);
  outproj_kernel<<<BT / 16, 256, 0, stream>>>(Hb, Wo, bo, out);
}

// Round 10
// 1381.501 us; speedup vs baseline: 1.6472x; 1.0152x over previous
//
#include <hip/hip_runtime.h>
#include <math.h>

#define NB 16
#define T  2048
#define D  512
#define BD 64
#define BT (NB*T)  // 32768

// workspace layout (float offsets)
#define OFF_K   0
#define OFF_V   (BT*BD)
#define OFF_Q   (2*BT*BD)
#define OFF_ETA (3*BT*BD)
#define OFF_H   (3*BT*BD + BT)
// total floats = 4*BT*BD + BT = 8,421,376  (~33.7 MB)

// gram scratch lives in d_out (64 MB; overwritten later by outproj):
// per 16-step chunk: KK[16*16] | KQ[16*16] | SC[16] | pad -> 544 floats
#define GSTRIDE 544
#define NCHUNK  (BT/16)   // 2048

#define RL(x, i) __int_as_float(__builtin_amdgcn_readlane(__float_as_int(x), (i)))

// ---------------- DPP full-wave sum, result broadcast to all lanes ----------
__device__ __forceinline__ float wave_allsum(float x) {
  x += __int_as_float(__builtin_amdgcn_update_dpp(
      0, __float_as_int(x), 0x111, 0xf, 0xf, true));   // row_shr:1
  x += __int_as_float(__builtin_amdgcn_update_dpp(
      0, __float_as_int(x), 0x112, 0xf, 0xf, true));   // row_shr:2
  x += __int_as_float(__builtin_amdgcn_update_dpp(
      0, __float_as_int(x), 0x114, 0xf, 0xf, true));   // row_shr:4
  x += __int_as_float(__builtin_amdgcn_update_dpp(
      0, __float_as_int(x), 0x118, 0xf, 0xf, true));   // row_shr:8
  x += __int_as_float(__builtin_amdgcn_update_dpp(
      0, __float_as_int(x), 0x142, 0xa, 0xf, false));  // row_bcast:15 -> rows 1,3
  x += __int_as_float(__builtin_amdgcn_update_dpp(
      0, __float_as_int(x), 0x143, 0xc, 0xf, false));  // row_bcast:31 -> rows 2,3
  return RL(x, 63);
}

// DS-only barrier: waits lgkmcnt(0) (all loop lgkm ops are DS), leaves vmcnt
// in flight. Proven r3/r4.
__device__ __forceinline__ void lds_barrier() {
  __builtin_amdgcn_sched_barrier(0);
  __builtin_amdgcn_s_waitcnt(0xC07F);  // vmcnt=63 (no wait), expcnt=7, lgkmcnt=0
  __builtin_amdgcn_s_barrier();
  __builtin_amdgcn_sched_barrier(0);
}

// -------- fused projection + eta + gram (proven r9: part of 1402us best) ---
__global__ __launch_bounds__(256) void proj_kernel(
    const float* __restrict__ x,
    const float* __restrict__ Wk, const float* __restrict__ bk,
    const float* __restrict__ Wv, const float* __restrict__ bv,
    const float* __restrict__ Wq, const float* __restrict__ bq,
    const float* __restrict__ lr_w, const float* __restrict__ lr_b,
    const float* __restrict__ ln_g, const float* __restrict__ ln_b,
    float* __restrict__ Kout, float* __restrict__ Vout,
    float* __restrict__ Qout, float* __restrict__ eta,
    float* __restrict__ G) {
  __shared__ __align__(16) float xs[16 * D];               // 32 KB
  __shared__ __align__(16) float sK[16][64], sQ[16][64], sV[16][64];  // 12 KB
  __shared__ float sg[64], sb[64];
  const int tid = threadIdx.x;
  const size_t row0 = (size_t)blockIdx.x * 16;
  const float4* xg = (const float4*)(x + row0 * D);
  float4* xs4 = (float4*)xs;
#pragma unroll
  for (int i = 0; i < 8; i++) xs4[i * 256 + tid] = xg[i * 256 + tid];
  if (tid < 64) { sg[tid] = ln_g[tid]; sb[tid] = ln_b[tid]; }
  __syncthreads();
  const int col = tid & 63;
  const int rg = tid >> 6;  // 4 row-groups of 4 rows
  const int lane = tid & 63;

  float ak0 = 0.f, ak1 = 0.f, ak2 = 0.f, ak3 = 0.f;
  float av0 = 0.f, av1 = 0.f, av2 = 0.f, av3 = 0.f;
  float aq0 = 0.f, aq1 = 0.f, aq2 = 0.f, aq3 = 0.f;
  for (int d = 0; d < D; d += 4) {
    float wk0 = Wk[(d + 0) * BD + col];
    float wk1 = Wk[(d + 1) * BD + col];
    float wk2 = Wk[(d + 2) * BD + col];
    float wk3 = Wk[(d + 3) * BD + col];
    float wv0 = Wv[(d + 0) * BD + col];
    float wv1 = Wv[(d + 1) * BD + col];
    float wv2 = Wv[(d + 2) * BD + col];
    float wv3 = Wv[(d + 3) * BD + col];
    float wq0 = Wq[(d + 0) * BD + col];
    float wq1 = Wq[(d + 1) * BD + col];
    float wq2 = Wq[(d + 2) * BD + col];
    float wq3 = Wq[(d + 3) * BD + col];
    const float* xb = xs + (rg * 4) * D + d;
    float4 x0 = *(const float4*)(xb);
    float4 x1 = *(const float4*)(xb + D);
    float4 x2 = *(const float4*)(xb + 2 * D);
    float4 x3 = *(const float4*)(xb + 3 * D);
    ak0 += x0.x * wk0 + x0.y * wk1 + x0.z * wk2 + x0.w * wk3;
    ak1 += x1.x * wk0 + x1.y * wk1 + x1.z * wk2 + x1.w * wk3;
    ak2 += x2.x * wk0 + x2.y * wk1 + x2.z * wk2 + x2.w * wk3;
    ak3 += x3.x * wk0 + x3.y * wk1 + x3.z * wk2 + x3.w * wk3;
    av0 += x0.x * wv0 + x0.y * wv1 + x0.z * wv2 + x0.w * wv3;
    av1 += x1.x * wv0 + x1.y * wv1 + x1.z * wv2 + x1.w * wv3;
    av2 += x2.x * wv0 + x2.y * wv1 + x2.z * wv2 + x2.w * wv3;
    av3 += x3.x * wv0 + x3.y * wv1 + x3.z * wv2 + x3.w * wv3;
    aq0 += x0.x * wq0 + x0.y * wq1 + x0.z * wq2 + x0.w * wq3;
    aq1 += x1.x * wq0 + x1.y * wq1 + x1.z * wq2 + x1.w * wq3;
    aq2 += x2.x * wq0 + x2.y * wq1 + x2.z * wq2 + x2.w * wq3;
    aq3 += x3.x * wq0 + x3.y * wq1 + x3.z * wq2 + x3.w * wq3;
  }
  float bbk = bk[col], bbv = bv[col], bbq = bq[col];
  const size_t r0 = row0 + rg * 4;
  float k0v = ak0 + bbk, k1v = ak1 + bbk, k2v = ak2 + bbk, k3v = ak3 + bbk;
  float v0v = av0 + bbv, v1v = av1 + bbv, v2v = av2 + bbv, v3v = av3 + bbv;
  float q0v = aq0 + bbq, q1v = aq1 + bbq, q2v = aq2 + bbq, q3v = aq3 + bbq;
  Kout[(r0 + 0) * BD + col] = k0v;
  Kout[(r0 + 1) * BD + col] = k1v;
  Kout[(r0 + 2) * BD + col] = k2v;
  Kout[(r0 + 3) * BD + col] = k3v;
  Vout[(r0 + 0) * BD + col] = v0v;
  Vout[(r0 + 1) * BD + col] = v1v;
  Vout[(r0 + 2) * BD + col] = v2v;
  Vout[(r0 + 3) * BD + col] = v3v;
  Qout[(r0 + 0) * BD + col] = q0v;
  Qout[(r0 + 1) * BD + col] = q1v;
  Qout[(r0 + 2) * BD + col] = q2v;
  Qout[(r0 + 3) * BD + col] = q3v;
  // stage K/V/Q tile to LDS for the gram phase
  const int lr = rg * 4;
  sK[lr + 0][col] = k0v; sK[lr + 1][col] = k1v;
  sK[lr + 2][col] = k2v; sK[lr + 3][col] = k3v;
  sV[lr + 0][col] = v0v; sV[lr + 1][col] = v1v;
  sV[lr + 2][col] = v2v; sV[lr + 3][col] = v3v;
  sQ[lr + 0][col] = q0v; sQ[lr + 1][col] = q1v;
  sQ[lr + 2][col] = q2v; sQ[lr + 3][col] = q3v;

  // ---- eta for this wave's 4 rows (identical math to old eta_kernel) ----
  {
    const float* lw = lr_w + lane * 8;
    float4 la = *(const float4*)lw;
    float4 lb = *(const float4*)(lw + 4);
    float lrb0 = lr_b[0];
#pragma unroll
    for (int j = 0; j < 4; j++) {
      const float* xr = xs + (size_t)(rg * 4 + j) * D + lane * 8;
      float4 a = *(const float4*)xr;
      float4 b2 = *(const float4*)(xr + 4);
      float p = a.x * la.x + a.y * la.y + a.z * la.z + a.w * la.w +
                b2.x * lb.x + b2.y * lb.y + b2.z * lb.z + b2.w * lb.w;
#pragma unroll
      for (int m = 32; m > 0; m >>= 1) p += __shfl_xor(p, m, 64);
      if (lane == 0) eta[row0 + rg * 4 + j] = 1.0f / (1.0f + expf(-(p + lrb0)));
    }
  }
  __syncthreads();

  // ---- gram phase: bit-identical to the old standalone gram_kernel ----
  const int gi = tid >> 4, gt = tid & 15;
  float kk = 0.f, kq = 0.f;
#pragma unroll
  for (int d = 0; d < 64; d += 4) {
    float4 a4 = *(const float4*)&sK[gi][d];
    float4 b4 = *(const float4*)&sK[gt][d];
    float4 c4 = *(const float4*)&sQ[gt][d];
    kk += a4.x * b4.x + a4.y * b4.y + a4.z * b4.z + a4.w * b4.w;
    kq += a4.x * c4.x + a4.y * c4.y + a4.z * c4.z + a4.w * c4.w;
  }
  size_t gb = (size_t)blockIdx.x * GSTRIDE;
  G[gb + gi * 16 + gt] = kk;
  G[gb + 256 + gi * 16 + gt] = kq;
  if (tid < 16) {
    float sc = 0.f;
    for (int d = 0; d < 64; d++)
      sc += sg[d] * (sK[tid][d] + sb[d] - sV[tid][d]);
    G[gb + 512 + tid] = sc;
  }
}

// ---------------- sequential TTT scan: chunked delta-rule, 4 waves --------
// FROZEN: exact r4 structure, measured 1096/1096/1094us across three runs.
// Five structural variants (r5-r8) all regressed; do not touch.
__global__ __launch_bounds__(256, 1)
void ttt_seq_kernel(
    const float* __restrict__ Kin, const float* __restrict__ Vin,
    const float* __restrict__ Qin, const float* __restrict__ eta_in,
    const float* __restrict__ W0, const float* __restrict__ ln_g,
    const float* __restrict__ ln_b, float* __restrict__ Hout,
    const float* __restrict__ gram) {
  __shared__ __align__(16) float2 part2[16][4][64];  // 32 KB partials
  __shared__ __align__(16) float kls[16][64];        // 4 KB k rows
  __shared__ __align__(16) float qls[16][64];        // 4 KB q rows
  const int tid = threadIdx.x;
  const int lane = tid & 63;
  const int wvu = __builtin_amdgcn_readfirstlane(tid) >> 6;
  const int b = blockIdx.x;

  // W slice: w[4i+j] = W0[lane*BD + 16*wvu + 4i+j]
  float w[16];
  {
    const float4* w04 = (const float4*)(W0 + (size_t)lane * BD + wvu * 16);
#pragma unroll
    for (int i = 0; i < 4; i++) {
      float4 t4 = w04[i];
      w[4 * i] = t4.x; w[4 * i + 1] = t4.y; w[4 * i + 2] = t4.z; w[4 * i + 3] = t4.w;
    }
  }
  const float g = ln_g[lane];
  const float bet = ln_b[lane];
  const float a = g * g;
  const float A2 = wave_allsum(a);

  size_t base = (size_t)b * T * BD;   // advances BD per step
  size_t ebase = (size_t)b * T;

  // per-lane rows of the current chunk (reloaded in-place for chunk+1 during
  // phase B, period-16 ring -> zero extra registers)
  float krow[16], qrow[16], vrow[16];
#pragma unroll
  for (int r = 0; r < 16; r++) {
    krow[r] = Kin[base + r * BD + lane];
    qrow[r] = Qin[base + r * BD + lane];
    vrow[r] = Vin[base + r * BD + lane];
  }
  float ev  = eta_in[ebase + lane];
  float evn = eta_in[ebase + 64 + lane];

  float u2sv[4], qsv[4];  // deferred phase-2 state (4 owned steps per wave)

  for (int c64 = 0; c64 < 32; c64++) {
    size_t eoff = (size_t)(c64 + 2) * 64;
    if (eoff >= T) eoff = 0;
    float ev2 = eta_in[ebase + eoff + lane];

    for (int cc = 0; cc < 4; cc++) {
      // ---- gram loads for this chunk (consumed in phase B; phase A covers) --
      const size_t gb = (size_t)(b * 128 + c64 * 4 + cc) * GSTRIDE;
      float KKr[15], KQr[16];
#pragma unroll
      for (int t = 0; t < 15; t++) KKr[t] = gram[gb + t * 16 + lane];
#pragma unroll
      for (int t = 0; t < 16; t++) KQr[t] = gram[gb + 256 + t * 16 + lane];
      float SCv = gram[gb + 512 + lane];

      // ---- phase A: stage rows to LDS (all waves write identical values:
      // benign; each wave's own in-order DS writes make its reads correct) --
#pragma unroll
      for (int r = 0; r < 16; r++) {
        kls[r][lane] = krow[r];
        qls[r][lane] = qrow[r];
      }
      // 3-deep uniform-read pipeline (broadcast ds_read_b128, conflict-free)
      float4 kuf[3][4], quf[3][4];
#pragma unroll
      for (int r = 0; r < 3; r++) {
        const float4* kp = (const float4*)&kls[r][wvu * 16];
        const float4* qp = (const float4*)&qls[r][wvu * 16];
#pragma unroll
        for (int i = 0; i < 4; i++) { kuf[r][i] = kp[i]; quf[r][i] = qp[i]; }
      }
      float u0[16], p0[16];
#pragma unroll
      for (int r = 0; r < 16; r++) {
        const int bf = r % 3;
        float uu0 = 0.f, uu1 = 0.f, uu2 = 0.f, uu3 = 0.f;
        float pp0 = 0.f, pp1 = 0.f, pp2 = 0.f, pp3 = 0.f;
#pragma unroll
        for (int i = 0; i < 4; i++) {
          uu0 += kuf[bf][i].x * w[4 * i + 0];
          uu1 += kuf[bf][i].y * w[4 * i + 1];
          uu2 += kuf[bf][i].z * w[4 * i + 2];
          uu3 += kuf[bf][i].w * w[4 * i + 3];
          pp0 += quf[bf][i].x * w[4 * i + 0];
          pp1 += quf[bf][i].y * w[4 * i + 1];
          pp2 += quf[bf][i].z * w[4 * i + 2];
          pp3 += quf[bf][i].w * w[4 * i + 3];
        }
        part2[r][wvu][lane] = make_float2((uu0 + uu1) + (uu2 + uu3),
                                          (pp0 + pp1) + (pp2 + pp3));
        if (r < 13) {
          const float4* kp = (const float4*)&kls[r + 3][wvu * 16];
          const float4* qp = (const float4*)&qls[r + 3][wvu * 16];
#pragma unroll
          for (int i = 0; i < 4; i++) { kuf[bf][i] = kp[i]; quf[bf][i] = qp[i]; }
        }
      }

      lds_barrier();  // partials visible

      // combine partials -> full u, p
#pragma unroll
      for (int r = 0; r < 16; r++) {
        float2 pA = part2[r][0][lane];
        float2 pB = part2[r][1][lane];
        float2 pC = part2[r][2][lane];
        float2 pD = part2[r][3][lane];
        u0[r] = (pA.x + pB.x) + (pC.x + pD.x);
        p0[r] = (pA.y + pB.y) + (pC.y + pD.y);
      }

      // ---- phase B: 16 serial steps, no barriers ----
#pragma unroll
      for (int t = 0; t < 16; t++) {
        float u = u0[t];
        float kcur = krow[t], vcur = vrow[t], qcur = qrow[t];
        float ecur = RL(ev, cc * 16 + t);
        float c0 = g * (kcur + bet - vcur);

        float Su   = wave_allsum(u);
        float Suu  = wave_allsum(u * u);
        float Sau  = wave_allsum(a * u);
        float Sauu = wave_allsum(a * u * u);
        float Scu  = wave_allsum(c0 * u);
        float Sc   = RL(SCv, t);

        float mu = Su * (1.0f / 64);
        float var = Suu * (1.0f / 64) - mu * mu;
        float rstd = rsqrtf(var + 1e-6f);
        float xh = (u - mu) * rstd;
        float Axh   = rstd * (Sau - mu * A2);
        float Scxh  = rstd * (Scu - mu * Sc);
        float Saxh2 = rstd * rstd * (Sauu - 2.0f * mu * Sau + mu * mu * A2);
        float s1 = (2.0f / 64) * (Sc + Axh);
        float s2 = (2.0f / 64) * (Scxh + Saxh2);
        float dxh = (2.0f / 64) * (c0 + a * xh);
        float dldu = rstd * (dxh - s1 * (1.0f / 64) - xh * (s2 * (1.0f / 64)));
        float coef = -ecur * dldu;

        // critical correction first: u for step t+1
        if (t < 15)
          u0[t + 1] += coef * RL(KKr[t], t + 1);
        // lazy corrections (off critical path)
#pragma unroll
        for (int s = t + 2; s < 16; s++)
          u0[s] += coef * RL(KKr[t], s);
#pragma unroll
        for (int s = t; s < 16; s++)
          p0[s] += coef * RL(KQr[t], s);

        // W-slice update via uniform LDS read of row t (off critical path;
        // next use of w is next chunk's phase A)
        {
          const float4* kp = (const float4*)&kls[t][wvu * 16];
#pragma unroll
          for (int i = 0; i < 4; i++) {
            float4 k4 = kp[i];
            w[4 * i + 0] += coef * k4.x;
            w[4 * i + 1] += coef * k4.y;
            w[4 * i + 2] += coef * k4.z;
            w[4 * i + 3] += coef * k4.w;
          }
        }

        if ((t & 3) == wvu) { u2sv[t >> 2] = p0[t]; qsv[t >> 2] = qcur; }

        // reload row t for the NEXT chunk (per-lane; 16 steps of cover)
        krow[t] = Kin[base + 16 * BD + lane];
        qrow[t] = Qin[base + 16 * BD + lane];
        vrow[t] = Vin[base + 16 * BD + lane];
        base += BD;
      }

      // ---- deferred phase-2 flush: each wave finalizes its 4 owned steps --
#pragma unroll
      for (int fi = 0; fi < 4; fi++) {
        float u2 = u2sv[fi];
        float Su2  = wave_allsum(u2);
        float Suu2 = wave_allsum(u2 * u2);
        float mu2 = Su2 * (1.0f / 64);
        float rstd2 = rsqrtf(Suu2 * (1.0f / 64) - mu2 * mu2 + 1e-6f);
        int tt = 4 * fi + wvu;
        Hout[base - (size_t)(16 - tt) * BD + lane] =
            qsv[fi] + (u2 - mu2) * rstd2 * g + bet;
      }

      // protect kls/qls/part2 (single-buffered) against next chunk's writes
      lds_barrier();
    }
    ev = evn; evn = ev2;
  }
}

// ---------------- out projection: z = H @ Wo + bo ----------------
// Round 14: 32 rows/block (grid 2048->1024) halves total Wo-load instruction
// count (128 dwords/thread amortized over 2x rows). Same kk4 loop and hv
// grouping -> per-output accumulation order bit-identical.
__global__ __launch_bounds__(256) void outproj_kernel(
    const float* __restrict__ H, const float* __restrict__ Wo,
    const float* __restrict__ bo, float* __restrict__ out) {
  __shared__ __align__(16) float ht[32 * BD];  // 8 KB
  const int tid = threadIdx.x;
  const size_t row0 = (size_t)blockIdx.x * 32;
#pragma unroll
  for (int i = 0; i < 2; i++)
    ((float4*)ht)[i * 256 + tid] = ((const float4*)(H + row0 * BD))[i * 256 + tid];
  __syncthreads();
  float acc0[32], acc1[32];
#pragma unroll
  for (int r = 0; r < 32; r++) { acc0[r] = 0.f; acc1[r] = 0.f; }
  for (int kk4 = 0; kk4 < 16; kk4++) {
    float w00 = Wo[(4 * kk4 + 0) * D + tid];
    float w01 = Wo[(4 * kk4 + 1) * D + tid];
    float w02 = Wo[(4 * kk4 + 2) * D + tid];
    float w03 = Wo[(4 * kk4 + 3) * D + tid];
    float w10 = Wo[(4 * kk4 + 0) * D + tid + 256];
    float w11 = Wo[(4 * kk4 + 1) * D + tid + 256];
    float w12 = Wo[(4 * kk4 + 2) * D + tid + 256];
    float w13 = Wo[(4 * kk4 + 3) * D + tid + 256];
#pragma unroll
    for (int r = 0; r < 32; r++) {
      float4 hv = *(const float4*)&ht[r * BD + 4 * kk4];
      acc0[r] += hv.x * w00;
      acc0[r] += hv.y * w01;
      acc0[r] += hv.z * w02;
      acc0[r] += hv.w * w03;
      acc1[r] += hv.x * w10;
      acc1[r] += hv.y * w11;
      acc1[r] += hv.z * w12;
      acc1[r] += hv.w * w13;
    }
  }
  float b0 = bo[tid], b1 = bo[tid + 256];
#pragma unroll
  for (int r = 0; r < 32; r++) {
    out[(row0 + r) * D + tid] = acc0[r] + b0;
    out[(row0 + r) * D + tid + 256] = acc1[r] + b1;
  }
}

extern "C" void kernel_launch(void* const* d_in, const int* in_sizes, int n_in,
                              void* d_out, int out_size, void* d_ws,
                              size_t ws_size, hipStream_t stream) {
  (void)in_sizes; (void)n_in; (void)out_size; (void)ws_size;
  const float* x    = (const float*)d_in[0];
  const float* Wk   = (const float*)d_in[1];
  const float* bk   = (const float*)d_in[2];
  const float* Wv   = (const float*)d_in[3];
  const float* bv   = (const float*)d_in[4];
  const float* Wq   = (const float*)d_in[5];
  const float* bq   = (const float*)d_in[6];
  const float* Wo   = (const float*)d_in[7];
  const float* bo   = (const float*)d_in[8];
  const float* ln_g = (const float*)d_in[9];
  const float* ln_b = (const float*)d_in[10];
  const float* lr_w = (const float*)d_in[11];
  const float* lr_b = (const float*)d_in[12];
  const float* W0   = (const float*)d_in[13];

  float* ws  = (float*)d_ws;
  float* Kb  = ws + OFF_K;
  float* Vb  = ws + OFF_V;
  float* Qb  = ws + OFF_Q;
  float* ETA = ws + OFF_ETA;
  float* Hb  = ws + OFF_H;
  float* out = (float*)d_out;
  float* GRAM = out;  // scratch inside d_out; overwritten later by outproj

  proj_kernel<<<NCHUNK, 256, 0, stream>>>(x, Wk, bk, Wv, bv, Wq, bq,
                                          lr_w, lr_b, ln_g, ln_b,
                                          Kb, Vb, Qb, ETA, GRAM);
  ttt_seq_kernel<<<NB, 256, 0, stream>>>(Kb, Vb, Qb, ETA, W0, ln_g, ln_b, Hb, GRAM);
  outproj_kernel<<<BT / 32, 256, 0, stream>>>(Hb, Wo, bo, out);
}